// Round 13
// baseline (767.906 us; speedup 1.0000x reference)
//
#include <hip/hip_runtime.h>
#include <cmath>

#define LEAK 0.2f
#define BN_EPS 1e-5f

static inline int cdiv(long long a, long long b){ return (int)((a + b - 1) / b); }

typedef __attribute__((ext_vector_type(8))) short bf16x8;
typedef __attribute__((ext_vector_type(4))) float f32x4;

// ---- bf16 helpers (manual, RNE) -------------------------------------------
__device__ __forceinline__ float bf2f(unsigned short u){
    return __uint_as_float(((unsigned int)u) << 16);
}
__device__ __forceinline__ unsigned short f2bf(float f){
    unsigned int u = __float_as_uint(f);
    u += 0x7FFFu + ((u >> 16) & 1u);
    return (unsigned short)(u >> 16);
}
__device__ __forceinline__ float edge_ex(float s, float d){
    float t = s + d;
    t = (t >= 0.f) ? t : LEAK * t;
    return __expf(t);
}

// async global->LDS, 16B per lane. LDS dest must be linear: wave-uniform base
// + lane*16 (m104). Source address is per-lane -> swizzle goes on the SOURCE.
#define GLOAD_LDS16(gsrc, ldst) \
    __builtin_amdgcn_global_load_lds( \
        (const __attribute__((address_space(1))) unsigned int*)(gsrc), \
        (__attribute__((address_space(3))) unsigned int*)(ldst), 16, 0, 0)

// ---------------------------------------------------------------------------
// MFMA bf16 GEMM (128x128 tile, BK=64, 4 waves x 4x4 16x16x32 MFMAs).
// m97 staging + BK=64 + both-sides XOR chunk swizzle (R4: 82us, 0 conflicts).
// XCD-aware 1D swizzle. grid.x = 8 * cdiv(NYT,8) * NX.  K % 64 == 0.
// R13: LDS-repack epilogue -- C tile staged in As/Bs (free after the K-loop's
// trailing barrier) with lq<<4 col-XOR (bank spread), then coalesced bf16x8
// stores (64 scattered 2B stores -> 8 x 16B per thread).
// ---------------------------------------------------------------------------
__global__ __launch_bounds__(256) void gemm_mfma(
    const unsigned short* __restrict__ A, const unsigned short* __restrict__ Bt,
    unsigned short* __restrict__ D, int M, int K, int lda, int ldb, int ldc,
    int NX, int NYT)
{
    const int id = blockIdx.x;
    const int xcd = id & 7;
    const int j = id >> 3;
    const int bx = j % NX;
    const int by = (j / NX) * 8 + xcd;
    if (by >= NYT) return;

    __shared__ unsigned short As[128 * 64];
    __shared__ unsigned short Bs[128 * 64];
    const int t = threadIdx.x;
    const int row0 = by * 128, col0 = bx * 128;
    const int lane = t & 63, wv = t >> 6;
    const int wm = (wv >> 1) << 6, wn = (wv & 1) << 6;
    const int lm = lane & 15, lq = lane >> 4;

    const int sr  = t >> 3;                       // 0..31
    const int scs = (t & 7) << 3;                 // LDS col in shorts (linear)
    const int gsw = (((t & 7) ^ (sr & 7)) << 3);  // global col in shorts
    const unsigned short* ap[4];
    const unsigned short* bp[4];
    unsigned short* la[4];
    unsigned short* lb[4];
    #pragma unroll
    for (int q = 0; q < 4; ++q) {
        int r = sr + q * 32;
        int gra = row0 + r; if (gra >= M) gra = M - 1;
        ap[q] = A  + (size_t)gra * lda + gsw;
        bp[q] = Bt + (size_t)(col0 + r) * ldb + gsw;
        la[q] = &As[r * 64 + scs];
        lb[q] = &Bs[r * 64 + scs];
    }

    f32x4 acc[4][4] = {};
    const int rx = lm & 7;                        // row&7 for this lane's reads

    for (int k0 = 0; k0 < K; k0 += 64) {
        #pragma unroll
        for (int q = 0; q < 4; ++q) {
            GLOAD_LDS16(ap[q] + k0, la[q]);
            GLOAD_LDS16(bp[q] + k0, lb[q]);
        }
        __syncthreads();

        #pragma unroll
        for (int kk = 0; kk < 2; ++kk) {
            const int ck = (((kk << 2) + lq) ^ rx) << 3;   // swizzled chunk col
            bf16x8 af[4], bfr[4];
            #pragma unroll
            for (int mi = 0; mi < 4; ++mi)
                af[mi] = *(const bf16x8*)&As[(wm + mi * 16 + lm) * 64 + ck];
            #pragma unroll
            for (int ni = 0; ni < 4; ++ni)
                bfr[ni] = *(const bf16x8*)&Bs[(wn + ni * 16 + lm) * 64 + ck];
            #pragma unroll
            for (int mi = 0; mi < 4; ++mi)
                #pragma unroll
                for (int ni = 0; ni < 4; ++ni)
                    acc[mi][ni] = __builtin_amdgcn_mfma_f32_16x16x32_bf16(
                        af[mi], bfr[ni], acc[mi][ni], 0, 0, 0);
        }
        __syncthreads();
    }
    // K-loop's trailing barrier: all ds_reads drained -> As/Bs reusable.

    // ---- epilogue: repack C tile via LDS for coalesced 16B stores ----------
    // writer: logical col c stored at physical c ^ (lq<<4), lq=(row>>2)&3
    // (spreads the 4 lq row-groups across banks -> 2-way only). XOR on bit 4
    // keeps 8-element chunks contiguous (chunk base is a multiple of 8).
    #pragma unroll
    for (int mi = 0; mi < 4; ++mi) {
        #pragma unroll
        for (int r = 0; r < 4; ++r) {
            int row = wm + mi * 16 + lq * 4 + r;
            unsigned short* base = (row < 64) ? &As[row * 128] : &Bs[(row - 64) * 128];
            #pragma unroll
            for (int ni = 0; ni < 4; ++ni) {
                int col = (wn + ni * 16 + lm) ^ (lq << 4);
                base[col] = f2bf(acc[mi][ni][r]);
            }
        }
    }
    __syncthreads();
    #pragma unroll
    for (int i = 0; i < 8; ++i) {
        int idx = i * 256 + t;                 // 0..2047: 128 rows x 16 chunks
        int row = idx >> 4;
        int lqr = (row >> 2) & 3;
        int c8l = (idx & 15) << 3;             // logical chunk col
        int c8p = c8l ^ (lqr << 4);            // physical (swizzled) col
        int grow = row0 + row;
        if (grow < M) {
            const unsigned short* base = (row < 64) ? &As[row * 128] : &Bs[(row - 64) * 128];
            bf16x8 v = *(const bf16x8*)&base[c8p];
            *(bf16x8*)(D + (size_t)grow * ldc + col0 + c8l) = v;
        }
    }
}

// ---------------------------------------------------------------------------
// Logits: C[M,8] = A[M,K] @ vat[8,K]^T (used for K=64, layer 1).
// ---------------------------------------------------------------------------
__global__ __launch_bounds__(256) void logits_valu(
    const unsigned short* __restrict__ A, const unsigned short* __restrict__ vat,
    float* __restrict__ C, int M, int K)
{
    __shared__ unsigned short vs[8 * 512];
    const int t = threadIdx.x;
    for (int i = t; i < K; i += 256)
        *(bf16x8*)&vs[i * 8] = *(const bf16x8*)(vat + (size_t)i * 8);
    __syncthreads();

    const int lane = t & 63;
    const int w = blockIdx.x * 4 + (t >> 6);
    const int Gl = K >> 3;                     // lanes per row (8 or 64)
    const int rpw = 64 / Gl;                   // rows per wave
    const int sub = lane / Gl;
    const int li = lane - sub * Gl;
    long long row = (long long)w * rpw + sub;
    if (row >= M) return;

    bf16x8 hv = *(const bf16x8*)(A + row * K + li * 8);
    float hf[8];
    #pragma unroll
    for (int j = 0; j < 8; ++j) hf[j] = bf2f((unsigned short)hv[j]);

    float s[8];
    #pragma unroll
    for (int o = 0; o < 8; ++o) {
        bf16x8 v = *(const bf16x8*)&vs[o * K + li * 8];
        float acc = 0.f;
        #pragma unroll
        for (int j = 0; j < 8; ++j) acc += hf[j] * bf2f((unsigned short)v[j]);
        s[o] = acc;
    }
    for (int off = Gl >> 1; off; off >>= 1) {
        #pragma unroll
        for (int o = 0; o < 8; ++o) s[o] += __shfl_xor(s[o], off);
    }
    #pragma unroll
    for (int o = 0; o < 8; ++o)
        if (li == o) C[row * 8 + o] = s[o];
}

// ---------------------------------------------------------------------------
// FUSED: relu(bn(g1b)) -> o1n bf16  AND  layer-2 logits (K=512) from the
// fp32 pre-rounding values. Wave per row; vat2 staged in LDS.
// ---------------------------------------------------------------------------
__global__ __launch_bounds__(256) void bn_apply_logits512(
    const unsigned short* __restrict__ g1b,
    const float* __restrict__ scale, const float* __restrict__ shift,
    const unsigned short* __restrict__ vat,
    unsigned short* __restrict__ o1n, float* __restrict__ C, int M)
{
    __shared__ unsigned short vs[8 * 512];
    const int t = threadIdx.x;
    for (int i = t; i < 512; i += 256)
        *(bf16x8*)&vs[i * 8] = *(const bf16x8*)(vat + (size_t)i * 8);
    __syncthreads();

    const int lane = t & 63;
    long long row = (long long)blockIdx.x * 4 + (t >> 6);
    if (row >= M) return;

    bf16x8 u = *(const bf16x8*)(g1b + row * 512 + lane * 8);
    float4 sc0 = *(const float4*)(scale + lane * 8);
    float4 sc1 = *(const float4*)(scale + lane * 8 + 4);
    float4 sh0 = *(const float4*)(shift + lane * 8);
    float4 sh1 = *(const float4*)(shift + lane * 8 + 4);
    float hf[8];
    hf[0] = fmaxf(bf2f((unsigned short)u[0]) * sc0.x + sh0.x, 0.f);
    hf[1] = fmaxf(bf2f((unsigned short)u[1]) * sc0.y + sh0.y, 0.f);
    hf[2] = fmaxf(bf2f((unsigned short)u[2]) * sc0.z + sh0.z, 0.f);
    hf[3] = fmaxf(bf2f((unsigned short)u[3]) * sc0.w + sh0.w, 0.f);
    hf[4] = fmaxf(bf2f((unsigned short)u[4]) * sc1.x + sh1.x, 0.f);
    hf[5] = fmaxf(bf2f((unsigned short)u[5]) * sc1.y + sh1.y, 0.f);
    hf[6] = fmaxf(bf2f((unsigned short)u[6]) * sc1.z + sh1.z, 0.f);
    hf[7] = fmaxf(bf2f((unsigned short)u[7]) * sc1.w + sh1.w, 0.f);
    bf16x8 o;
    #pragma unroll
    for (int j = 0; j < 8; ++j) o[j] = (short)f2bf(hf[j]);
    *(bf16x8*)(o1n + row * 512 + lane * 8) = o;

    float s[8];
    #pragma unroll
    for (int oo = 0; oo < 8; ++oo) {
        bf16x8 v = *(const bf16x8*)&vs[oo * 512 + lane * 8];
        float acc = 0.f;
        #pragma unroll
        for (int j = 0; j < 8; ++j) acc += hf[j] * bf2f((unsigned short)v[j]);
        s[oo] = acc;
    }
    #pragma unroll
    for (int off = 32; off; off >>= 1) {
        #pragma unroll
        for (int oo = 0; oo < 8; ++oo) s[oo] += __shfl_xor(s[oo], off);
    }
    #pragma unroll
    for (int oo = 0; oo < 8; ++oo)
        if (lane == oo) C[row * 8 + oo] = s[oo];
}

// ---------------------------------------------------------------------------
// MEGA-PREP: all weight conversions + x cast + vat + cursor init + group LB
// in ONE launch, segmented by blockIdx ranges (each branch is block-uniform).
// ---------------------------------------------------------------------------
__global__ __launch_bounds__(256) void prep_all(
    const float* __restrict__ W1, const float* __restrict__ W2,
    const float* __restrict__ Wg, const float* __restrict__ x,
    const float* __restrict__ a1s, const float* __restrict__ a1d,
    const float* __restrict__ a2s, const float* __restrict__ a2d,
    const int* __restrict__ batch,
    unsigned short* __restrict__ W1bdt, unsigned short* __restrict__ W2t,
    unsigned short* __restrict__ Wgt, unsigned short* __restrict__ xb,
    unsigned short* __restrict__ vat1, unsigned short* __restrict__ vat2,
    int* __restrict__ cursor, int* __restrict__ gptr,
    int N, int G_,
    int c0, int c1, int c2, int c3, int c4, int c5, int c6)
{
    const int t = threadIdx.x;
    const int bid = blockIdx.x;
    if (bid < c0) {
        int i = bid * 256 + t;                 // exactly 512*256
        int o = i >> 8, k = i & 255;
        unsigned short v = 0;
        if ((k >> 6) == (o >> 7)) v = f2bf(W1[(size_t)(k & 63) * 512 + o]);
        W1bdt[i] = v;
    } else if (bid < c1) {
        int i = (bid - c0) * 256 + t;          // exactly 512*1024
        int k = i >> 10, n = i & 1023;
        W2t[(size_t)n * 512 + k] = f2bf(W2[i]);
    } else if (bid < c2) {
        int i = (bid - c1) * 256 + t;          // exactly 1024*256
        int k = i >> 8, n = i & 255;
        Wgt[(size_t)n * 1024 + k] = f2bf(Wg[i]);
    } else if (bid < c3) {
        int i = (bid - c2) * 256 + t;
        if (i < N * 16) {
            float4 v = *reinterpret_cast<const float4*>(x + (size_t)i * 4);
            ushort4 o = { f2bf(v.x), f2bf(v.y), f2bf(v.z), f2bf(v.w) };
            *reinterpret_cast<ushort4*>(xb + (size_t)i * 4) = o;
        }
    } else if (bid < c4) {
        int w = (((bid - c3) * 256 + t) >> 6);
        int lane = t & 63;
        int k = w >> 2, h = w & 3;
        const float* wp = W1 + (size_t)k * 512 + h * 128;
        const float* as = a1s + h * 128;
        const float* ad = a1d + h * 128;
        float s = 0.f, d = 0.f;
        for (int c = lane; c < 128; c += 64) {
            float v = wp[c];
            s += v * as[c];
            d += v * ad[c];
        }
        #pragma unroll
        for (int off = 32; off; off >>= 1) {
            s += __shfl_down(s, off);
            d += __shfl_down(d, off);
        }
        if (lane == 0) {
            vat1[(size_t)h * 64 + k] = f2bf(s);
            vat1[(size_t)(4 + h) * 64 + k] = f2bf(d);
        }
    } else if (bid < c5) {
        int w = (((bid - c4) * 256 + t) >> 6);
        int lane = t & 63;
        int k = w >> 2, h = w & 3;
        const float* wp = W2 + (size_t)k * 1024 + h * 256;
        const float* as = a2s + h * 256;
        const float* ad = a2d + h * 256;
        float s = 0.f, d = 0.f;
        for (int c = lane; c < 256; c += 64) {
            float v = wp[c];
            s += v * as[c];
            d += v * ad[c];
        }
        #pragma unroll
        for (int off = 32; off; off >>= 1) {
            s += __shfl_down(s, off);
            d += __shfl_down(d, off);
        }
        if (lane == 0) {
            vat2[(size_t)h * 512 + k] = f2bf(s);
            vat2[(size_t)(4 + h) * 512 + k] = f2bf(d);
        }
    } else if (bid < c6) {
        int i = (bid - c5) * 256 + t;
        if (i < N) cursor[i] = 1;
    } else {
        int g = (bid - c6) * 256 + t;
        if (g > G_) return;
        if (g == G_) { gptr[G_] = N; return; }
        int lo = 0, hi = N;
        while (lo < hi) { int mid = (lo + hi) >> 1; if (batch[mid] < g) lo = mid + 1; else hi = mid; }
        gptr[g] = lo;
    }
}

// ---------------------------------------------------------------------------
// Small-M fp32 GEMM, Nc = 128: one output/thread, 2 rows/block, A in LDS.
// Optional fused BN stats (per-thread atomicAdd; cheap -- no extra sync).
// ---------------------------------------------------------------------------
template<bool RELU>
__global__ __launch_bounds__(256) void gemm_small(
    const float* __restrict__ A, const float* __restrict__ B,
    const float* __restrict__ bias, float* __restrict__ C,
    int M, int K, int lda, int ldb, int ldc,
    float* __restrict__ ps, float* __restrict__ pq)
{
    __shared__ float As[2][640];
    const int t = threadIdx.x;
    const int r = t >> 7, c = t & 127;
    const int row0 = blockIdx.x * 2;
    for (int i = t; i < 2 * K; i += 256) {
        int rr = i / K, kk = i - rr * K;
        int gr = row0 + rr;
        As[rr][kk] = (gr < M) ? A[(size_t)gr * lda + kk] : 0.f;
    }
    __syncthreads();
    float acc0 = 0.f, acc1 = 0.f;
    for (int k = 0; k < K; k += 8) {
        float4 a0 = *reinterpret_cast<const float4*>(&As[r][k]);
        float4 a1 = *reinterpret_cast<const float4*>(&As[r][k + 4]);
        acc0 += a0.x * B[(size_t)(k + 0) * ldb + c];
        acc1 += a0.y * B[(size_t)(k + 1) * ldb + c];
        acc0 += a0.z * B[(size_t)(k + 2) * ldb + c];
        acc1 += a0.w * B[(size_t)(k + 3) * ldb + c];
        acc0 += a1.x * B[(size_t)(k + 4) * ldb + c];
        acc1 += a1.y * B[(size_t)(k + 5) * ldb + c];
        acc0 += a1.z * B[(size_t)(k + 6) * ldb + c];
        acc1 += a1.w * B[(size_t)(k + 7) * ldb + c];
    }
    int row = row0 + r;
    if (row < M) {
        float v = acc0 + acc1;
        if (bias) v += bias[c];
        if (RELU) v = fmaxf(v, 0.f);
        C[(size_t)row * ldc + c] = v;
        if (ps) {
            size_t slot = (size_t)(blockIdx.x & 255) * 128 + c;
            atomicAdd(&ps[slot], v);
            atomicAdd(&pq[slot], v * v);
        }
    }
}

// ============================ CSR build ====================================
__device__ __forceinline__ int e_src(const int* es, int E, int k){ return k < E ? es[k] : k - E; }
__device__ __forceinline__ int e_dst(const int* ed, int E, int k){ return k < E ? ed[k] : k - E; }

__global__ void hist_dst(const int* __restrict__ ed, int E, int* __restrict__ cnt)
{
    int k = blockIdx.x * blockDim.x + threadIdx.x;
    if (k < E) atomicAdd(&cnt[ed[k]], 1);
}

__global__ __launch_bounds__(256) void scan_blk(const int* __restrict__ cnt,
                                                int* __restrict__ rowptr,
                                                int* __restrict__ bsums, int n)
{
    __shared__ int ts[256];
    const int t = threadIdx.x;
    const int i0 = blockIdx.x * 1024 + t * 4;
    int4 v = {0, 0, 0, 0};
    if (i0 + 3 < n) v = *reinterpret_cast<const int4*>(cnt + i0);
    else {
        if (i0 + 0 < n) v.x = cnt[i0 + 0];
        if (i0 + 1 < n) v.y = cnt[i0 + 1];
        if (i0 + 2 < n) v.z = cnt[i0 + 2];
        if (i0 + 3 < n) v.w = cnt[i0 + 3];
    }
    int lsum = v.x + v.y + v.z + v.w;
    ts[t] = lsum;
    __syncthreads();
    #pragma unroll
    for (int off = 1; off < 256; off <<= 1) {
        int u = (t >= off) ? ts[t - off] : 0;
        __syncthreads();
        ts[t] += u;
        __syncthreads();
    }
    int excl = ts[t] - lsum;
    if (i0 + 0 < n) rowptr[i0 + 0] = excl;
    if (i0 + 1 < n) rowptr[i0 + 1] = excl + v.x;
    if (i0 + 2 < n) rowptr[i0 + 2] = excl + v.x + v.y;
    if (i0 + 3 < n) rowptr[i0 + 3] = excl + v.x + v.y + v.z;
    if (t == 255) bsums[blockIdx.x] = ts[255];
}

__global__ __launch_bounds__(256) void scan_tops(int* __restrict__ bsums,
                                                 int* __restrict__ rowptr, int nb, int n)
{
    __shared__ int ts[256];
    const int t = threadIdx.x;
    int v = (t < nb) ? bsums[t] : 0;
    ts[t] = v;
    __syncthreads();
    #pragma unroll
    for (int off = 1; off < 256; off <<= 1) {
        int u = (t >= off) ? ts[t - off] : 0;
        __syncthreads();
        ts[t] += u;
        __syncthreads();
    }
    if (t < nb) bsums[t] = ts[t] - v;
    if (t == 255) rowptr[n] = ts[255];
}

__global__ void scan_add(int* __restrict__ rowptr, int* __restrict__ cursor,
                         const int* __restrict__ bsums, int n)
{
    int i = blockIdx.x * blockDim.x + threadIdx.x;
    if (i >= n) return;
    int r = rowptr[i] + bsums[i >> 10];
    rowptr[i] = r;
    cursor[i] = r;
}

// scatter (no dstarr) + dinv, one launch (blockIdx split)
__global__ void csr_scatter_dinv(const int* __restrict__ es, const int* __restrict__ ed,
                                 int E, int Etot, int* __restrict__ cursor,
                                 int* __restrict__ col,
                                 const int* __restrict__ rowptr,
                                 float* __restrict__ dinv, int N, int NBsc)
{
    const int bid = blockIdx.x;
    const int t = threadIdx.x;
    if (bid < NBsc) {
        int k = bid * 256 + t;
        if (k >= Etot) return;
        int sn = e_src(es, E, k), dn = e_dst(ed, E, k);
        int pos = atomicAdd(&cursor[dn], 1);
        col[pos] = sn;
    } else {
        int i = (bid - NBsc) * 256 + t;
        if (i < N) dinv[i] = rsqrtf(fmaxf((float)(rowptr[i + 1] - rowptr[i]), 1.f));
    }
}

// ====== layer-1 AGGREGATE-FIRST gather, exp fused, 2-edge ILP unroll =======
__global__ void gat_agg4_64(const int* __restrict__ rowptr, const int* __restrict__ col,
                            const unsigned short* __restrict__ xb,
                            const float* __restrict__ alsd,
                            unsigned short* __restrict__ agg, int N)
{
    int w = (int)(((long long)blockIdx.x * blockDim.x + threadIdx.x) >> 6);
    int lane = threadIdx.x & 63;
    if (w >= N) return;
    float4 dt = *reinterpret_cast<const float4*>(alsd + (size_t)w * 8 + 4);
    int r0 = rowptr[w], r1 = rowptr[w + 1];
    float a0 = 0.f, a1 = 0.f, a2 = 0.f, a3 = 0.f;
    float s0 = 0.f, s1 = 0.f, s2 = 0.f, s3 = 0.f;
    int e = r0;
    for (; e + 1 < r1; e += 2) {
        int snA = col[e], snB = col[e + 1];
        float4 stA = *reinterpret_cast<const float4*>(alsd + (size_t)snA * 8);
        float4 stB = *reinterpret_cast<const float4*>(alsd + (size_t)snB * 8);
        float xA = bf2f(xb[(size_t)snA * 64 + lane]);
        float xB = bf2f(xb[(size_t)snB * 64 + lane]);
        float eA0 = edge_ex(stA.x, dt.x), eB0 = edge_ex(stB.x, dt.x);
        float eA1 = edge_ex(stA.y, dt.y), eB1 = edge_ex(stB.y, dt.y);
        float eA2 = edge_ex(stA.z, dt.z), eB2 = edge_ex(stB.z, dt.z);
        float eA3 = edge_ex(stA.w, dt.w), eB3 = edge_ex(stB.w, dt.w);
        a0 += eA0 * xA + eB0 * xB;  s0 += eA0 + eB0;
        a1 += eA1 * xA + eB1 * xB;  s1 += eA1 + eB1;
        a2 += eA2 * xA + eB2 * xB;  s2 += eA2 + eB2;
        a3 += eA3 * xA + eB3 * xB;  s3 += eA3 + eB3;
    }
    if (e < r1) {
        int sn = col[e];
        float4 st = *reinterpret_cast<const float4*>(alsd + (size_t)sn * 8);
        float xA = bf2f(xb[(size_t)sn * 64 + lane]);
        float e0 = edge_ex(st.x, dt.x);
        float e1 = edge_ex(st.y, dt.y);
        float e2 = edge_ex(st.z, dt.z);
        float e3 = edge_ex(st.w, dt.w);
        a0 += e0 * xA; s0 += e0;
        a1 += e1 * xA; s1 += e1;
        a2 += e2 * xA; s2 += e2;
        a3 += e3 * xA; s3 += e3;
    }
    unsigned short* op = agg + (size_t)w * 256 + lane;
    op[0]   = f2bf(a0 / fmaxf(s0, 1e-16f));
    op[64]  = f2bf(a1 / fmaxf(s1, 1e-16f));
    op[128] = f2bf(a2 / fmaxf(s2, 1e-16f));
    op[192] = f2bf(a3 / fmaxf(s3, 1e-16f));
}

// ====== layer-2 gather, TWO heads per pass, exp fused, FUSED BN STATS,
// ====== 2-edge ILP unroll. ps/pq per-site regions, zeroed once up front. ===
__global__ __launch_bounds__(256) void gat_gather512_ex(
    const int* __restrict__ rowptr, const int* __restrict__ col,
    const unsigned short* __restrict__ h, int ldh,
    const float* __restrict__ alsd, int pr,
    unsigned short* __restrict__ out,
    float* __restrict__ ps, float* __restrict__ pq, int N)
{
    const int t = threadIdx.x;
    const int lane = t & 63;
    const int wv = t >> 6;
    int w = (int)(((long long)blockIdx.x * 256 + t) >> 6);
    const bool valid = (w < N);

    float v0=0.f,v1=0.f,v2=0.f,v3=0.f;      // head slot 0 normalized values
    float u0=0.f,u1=0.f,u2=0.f,u3=0.f;      // head slot 1
    if (valid) {
        float2 dt = *reinterpret_cast<const float2*>(alsd + (size_t)w * 8 + 4 + 2 * pr);
        int r0 = rowptr[w], r1 = rowptr[w + 1];
        float s0 = 0.f, s1 = 0.f;
        float a00=0.f,a01=0.f,a02=0.f,a03=0.f;
        float a10=0.f,a11=0.f,a12=0.f,a13=0.f;
        int e = r0;
        for (; e + 1 < r1; e += 2) {
            int snA = col[e], snB = col[e + 1];
            float2 stA = *reinterpret_cast<const float2*>(alsd + (size_t)snA * 8 + 2 * pr);
            float2 stB = *reinterpret_cast<const float2*>(alsd + (size_t)snB * 8 + 2 * pr);
            const unsigned short* pA = h + (size_t)snA * ldh + lane * 4;
            const unsigned short* pB = h + (size_t)snB * ldh + lane * 4;
            ushort4 hA0 = *reinterpret_cast<const ushort4*>(pA);
            ushort4 hA1 = *reinterpret_cast<const ushort4*>(pA + 256);
            ushort4 hB0 = *reinterpret_cast<const ushort4*>(pB);
            ushort4 hB1 = *reinterpret_cast<const ushort4*>(pB + 256);
            float eA0 = edge_ex(stA.x, dt.x), eB0 = edge_ex(stB.x, dt.x);
            float eA1 = edge_ex(stA.y, dt.y), eB1 = edge_ex(stB.y, dt.y);
            s0 += eA0 + eB0; s1 += eA1 + eB1;
            a00 += bf2f(hA0.x) * eA0 + bf2f(hB0.x) * eB0;
            a01 += bf2f(hA0.y) * eA0 + bf2f(hB0.y) * eB0;
            a02 += bf2f(hA0.z) * eA0 + bf2f(hB0.z) * eB0;
            a03 += bf2f(hA0.w) * eA0 + bf2f(hB0.w) * eB0;
            a10 += bf2f(hA1.x) * eA1 + bf2f(hB1.x) * eB1;
            a11 += bf2f(hA1.y) * eA1 + bf2f(hB1.y) * eB1;
            a12 += bf2f(hA1.z) * eA1 + bf2f(hB1.z) * eB1;
            a13 += bf2f(hA1.w) * eA1 + bf2f(hB1.w) * eB1;
        }
        if (e < r1) {
            int sn = col[e];
            float2 st = *reinterpret_cast<const float2*>(alsd + (size_t)sn * 8 + 2 * pr);
            float e0 = edge_ex(st.x, dt.x);
            float e1 = edge_ex(st.y, dt.y);
            const unsigned short* p = h + (size_t)sn * ldh + lane * 4;
            ushort4 h0 = *reinterpret_cast<const ushort4*>(p);
            ushort4 h1 = *reinterpret_cast<const ushort4*>(p + 256);
            s0 += e0; s1 += e1;
            a00 += bf2f(h0.x) * e0; a01 += bf2f(h0.y) * e0;
            a02 += bf2f(h0.z) * e0; a03 += bf2f(h0.w) * e0;
            a10 += bf2f(h1.x) * e1; a11 += bf2f(h1.y) * e1;
            a12 += bf2f(h1.z) * e1; a13 += bf2f(h1.w) * e1;
        }
        float i0 = 1.f / fmaxf(s0, 1e-16f);
        float i1 = 1.f / fmaxf(s1, 1e-16f);
        v0 = a00*i0; v1 = a01*i0; v2 = a02*i0; v3 = a03*i0;
        u0 = a10*i1; u1 = a11*i1; u2 = a12*i1; u3 = a13*i1;
        ushort4 o0 = { f2bf(v0), f2bf(v1), f2bf(v2), f2bf(v3) };
        ushort4 o1 = { f2bf(u0), f2bf(u1), f2bf(u2), f2bf(u3) };
        unsigned short* op = out + (size_t)w * 512 + lane * 4;
        *reinterpret_cast<ushort4*>(op)       = o0;
        *reinterpret_cast<ushort4*>(op + 256) = o1;
    }

    __shared__ float ls[4][512];
    __shared__ float lq[4][512];
    int c0 = lane * 4;
    ls[wv][c0+0]=v0; ls[wv][c0+1]=v1; ls[wv][c0+2]=v2; ls[wv][c0+3]=v3;
    ls[wv][256+c0+0]=u0; ls[wv][256+c0+1]=u1; ls[wv][256+c0+2]=u2; ls[wv][256+c0+3]=u3;
    lq[wv][c0+0]=v0*v0; lq[wv][c0+1]=v1*v1; lq[wv][c0+2]=v2*v2; lq[wv][c0+3]=v3*v3;
    lq[wv][256+c0+0]=u0*u0; lq[wv][256+c0+1]=u1*u1; lq[wv][256+c0+2]=u2*u2; lq[wv][256+c0+3]=u3*u3;
    __syncthreads();
    const size_t slot = (size_t)(blockIdx.x & 255) * 512;
    #pragma unroll
    for (int c = t; c < 512; c += 256) {
        float s = ls[0][c] + ls[1][c] + ls[2][c] + ls[3][c];
        float q = lq[0][c] + lq[1][c] + lq[2][c] + lq[3][c];
        atomicAdd(&ps[slot + c], s);
        atomicAdd(&pq[slot + c], q);
    }
}

// ====== GCN gather (C=256), FUSED BN STATS =================================
__global__ __launch_bounds__(256) void gcn_gather256(
    const int* __restrict__ rowptr, const int* __restrict__ col,
    const unsigned short* __restrict__ h,
    const float* __restrict__ dinv,
    unsigned short* __restrict__ out,
    float* __restrict__ ps, float* __restrict__ pq, int N)
{
    const int t = threadIdx.x;
    const int lane = t & 63;
    const int wv = t >> 6;
    int w = (int)(((long long)blockIdx.x * 256 + t) >> 6);
    const bool valid = (w < N);

    float v0=0.f,v1=0.f,v2=0.f,v3=0.f;
    if (valid) {
        int r0 = rowptr[w], r1 = rowptr[w + 1];
        float a0 = 0.f, a1 = 0.f, a2 = 0.f, a3 = 0.f;
        int e = r0;
        for (; e + 1 < r1; e += 2) {
            int sn0 = col[e], sn1 = col[e + 1];
            float w0 = dinv[sn0], w1 = dinv[sn1];
            ushort4 hv0 = *reinterpret_cast<const ushort4*>(h + (size_t)sn0 * 256 + lane * 4);
            ushort4 hv1 = *reinterpret_cast<const ushort4*>(h + (size_t)sn1 * 256 + lane * 4);
            a0 += bf2f(hv0.x) * w0 + bf2f(hv1.x) * w1;
            a1 += bf2f(hv0.y) * w0 + bf2f(hv1.y) * w1;
            a2 += bf2f(hv0.z) * w0 + bf2f(hv1.z) * w1;
            a3 += bf2f(hv0.w) * w0 + bf2f(hv1.w) * w1;
        }
        if (e < r1) {
            int sn = col[e];
            float wv2 = dinv[sn];
            ushort4 hv = *reinterpret_cast<const ushort4*>(h + (size_t)sn * 256 + lane * 4);
            a0 += bf2f(hv.x) * wv2; a1 += bf2f(hv.y) * wv2;
            a2 += bf2f(hv.z) * wv2; a3 += bf2f(hv.w) * wv2;
        }
        float dn = dinv[w];
        v0 = a0 * dn; v1 = a1 * dn; v2 = a2 * dn; v3 = a3 * dn;
        ushort4 o = { f2bf(v0), f2bf(v1), f2bf(v2), f2bf(v3) };
        *reinterpret_cast<ushort4*>(out + (size_t)w * 256 + lane * 4) = o;
    }

    __shared__ float ls[4][256];
    __shared__ float lq[4][256];
    int c0 = lane * 4;
    ls[wv][c0+0]=v0; ls[wv][c0+1]=v1; ls[wv][c0+2]=v2; ls[wv][c0+3]=v3;
    lq[wv][c0+0]=v0*v0; lq[wv][c0+1]=v1*v1; lq[wv][c0+2]=v2*v2; lq[wv][c0+3]=v3*v3;
    __syncthreads();
    const size_t slot = (size_t)(blockIdx.x & 255) * 256;
    if (t < 256) {
        int c = t;
        float s = ls[0][c] + ls[1][c] + ls[2][c] + ls[3][c];
        float q = lq[0][c] + lq[1][c] + lq[2][c] + lq[3][c];
        atomicAdd(&ps[slot + c], s);
        atomicAdd(&pq[slot + c], q);
    }
}

// ---- BN stats, bf16 input with row stride ldx ------------------------------
template<int D>
__global__ __launch_bounds__(256) void bn_part_bf(
    const unsigned short* __restrict__ x, int ldx,
    float* __restrict__ ps, float* __restrict__ pq, int M, int Y)
{
    constexpr int DG = D / 4;
    constexpr int P  = 256 / DG;
    const int t = threadIdx.x;
    const int cg = t % DG, ph = t / DG;
    const int y = blockIdx.y;
    const int rows_per = (M + Y - 1) / Y;
    const int r0 = y * rows_per;
    const int r1 = min(r0 + rows_per, M);
    float s0=0,s1=0,s2=0,s3=0,q0=0,q1=0,q2=0,q3=0;
    for (int r = r0 + ph; r < r1; r += P) {
        ushort4 u = *reinterpret_cast<const ushort4*>(x + (size_t)r * ldx + cg * 4);
        float vx = bf2f(u.x), vy = bf2f(u.y), vz = bf2f(u.z), vw = bf2f(u.w);
        s0+=vx; s1+=vy; s2+=vz; s3+=vw;
        q0+=vx*vx; q1+=vy*vy; q2+=vz*vz; q3+=vw*vw;
    }
    __shared__ float ls[P][D];
    __shared__ float lq[P][D];
    ls[ph][cg*4+0]=s0; ls[ph][cg*4+1]=s1; ls[ph][cg*4+2]=s2; ls[ph][cg*4+3]=s3;
    lq[ph][cg*4+0]=q0; lq[ph][cg*4+1]=q1; lq[ph][cg*4+2]=q2; lq[ph][cg*4+3]=q3;
    __syncthreads();
    if (ph == 0) {
        #pragma unroll
        for (int j = 0; j < 4; ++j) {
            float ss = 0.f, qq = 0.f;
            #pragma unroll
            for (int p = 0; p < P; ++p) { ss += ls[p][cg*4+j]; qq += lq[p][cg*4+j]; }
            ps[(size_t)y * D + cg*4 + j] = ss;
            pq[(size_t)y * D + cg*4 + j] = qq;
        }
    }
}

// ---- BN finalize: PARALLEL over column groups (grid.x = D/64) -------------
template<int D>
__global__ __launch_bounds__(256) void bn_reduce_fin(
    const float* __restrict__ ps, const float* __restrict__ pq,
    const float* __restrict__ g, const float* __restrict__ b,
    float* __restrict__ scale, float* __restrict__ shift, int Y, float invM)
{
    const int t = threadIdx.x;
    const int cl = t & 63;
    const int c = blockIdx.x * 64 + cl;
    const int ph = t >> 6;                 // 0..3
    float s = 0.f, q = 0.f;
    for (int y = ph; y < Y; y += 4) {
        s += ps[(size_t)y * D + c];
        q += pq[(size_t)y * D + c];
    }
    __shared__ float ls[4][64];
    __shared__ float lq[4][64];
    ls[ph][cl] = s; lq[ph][cl] = q;
    __syncthreads();
    if (ph == 0) {
        s = ls[0][cl] + ls[1][cl] + ls[2][cl] + ls[3][cl];
        q = lq[0][cl] + lq[1][cl] + lq[2][cl] + lq[3][cl];
        float mu = s * invM;
        float var = q * invM - mu * mu;
        float rs = rsqrtf(var + BN_EPS) * g[c];
        scale[c] = rs;
        shift[c] = b[c] - mu * rs;
    }
}

// relu(bn(x)): bf16 in (row stride ldx) -> bf16 out (row stride ldd)
__global__ void bn_apply_bfbf(const unsigned short* __restrict__ x,
                              const float* __restrict__ scale, const float* __restrict__ shift,
                              unsigned short* __restrict__ dst, int total4, int Cb4,
                              int ldx, int ldd)
{
    int i = blockIdx.x * blockDim.x + threadIdx.x;
    if (i >= total4) return;
    int r = i / Cb4, c4 = (i - r * Cb4) * 4;
    ushort4 u = *reinterpret_cast<const ushort4*>(x + (size_t)r * ldx + c4);
    float4 sc = *reinterpret_cast<const float4*>(scale + c4);
    float4 sh = *reinterpret_cast<const float4*>(shift + c4);
    ushort4 o;
    o.x = f2bf(fmaxf(bf2f(u.x) * sc.x + sh.x, 0.f));
    o.y = f2bf(fmaxf(bf2f(u.y) * sc.y + sh.y, 0.f));
    o.z = f2bf(fmaxf(bf2f(u.z) * sc.z + sh.z, 0.f));
    o.w = f2bf(fmaxf(bf2f(u.w) * sc.w + sh.w, 0.f));
    *reinterpret_cast<ushort4*>(dst + (size_t)r * ldd + c4) = o;
}

// ---- Pooling (BN3+relu fused) AND solvent MLP, one launch (blockIdx split) -
__global__ __launch_bounds__(256) void pool_solv(
    const unsigned short* __restrict__ h,
    const float* __restrict__ scale, const float* __restrict__ shift,
    const int* __restrict__ gptr, float* __restrict__ z, int G_,
    const float* __restrict__ sfp, const float* __restrict__ Wsm,
    const float* __restrict__ bsm)
{
    __shared__ float As[2][640];
    const int t = threadIdx.x;
    const int bid = blockIdx.x;
    if (bid < G_) {
        // ---- pooling with fused BN3 apply+relu (2-row ILP) ----
        int g = bid;
        int c = t;
        int r0 = gptr[g], r1 = gptr[g + 1];
        float sc = scale[c], sh = shift[c];
        float s = 0.f, m = 0.f;
        int i = r0;
        for (; i + 1 < r1; i += 2) {
            float v0 = fmaxf(bf2f(h[(size_t)i * 256 + c]) * sc + sh, 0.f);
            float v1 = fmaxf(bf2f(h[(size_t)(i + 1) * 256 + c]) * sc + sh, 0.f);
            s += v0 + v1;
            m = fmaxf(m, fmaxf(v0, v1));
        }
        if (i < r1) {
            float v = fmaxf(bf2f(h[(size_t)i * 256 + c]) * sc + sh, 0.f);
            s += v;
            m = fmaxf(m, v);
        }
        float cnt = fmaxf((float)(r1 - r0), 1.f);
        z[(size_t)g * 640 + c] = s / cnt;
        z[(size_t)g * 640 + 256 + c] = m;
    } else {
        // ---- solvent MLP: relu(sfp @ Wsm + bsm) -> z[:,512:640], K=128 ----
        const int r = t >> 7, c = t & 127;
        const int row0 = (bid - G_) * 2;
        for (int i = t; i < 256; i += 256) {
            int rr = i >> 7, kk = i & 127;
            int gr = row0 + rr;
            As[rr][kk] = (gr < G_) ? sfp[(size_t)gr * 128 + kk] : 0.f;
        }
        __syncthreads();
        float acc0 = 0.f, acc1 = 0.f;
        for (int k = 0; k < 128; k += 8) {
            float4 a0 = *reinterpret_cast<const float4*>(&As[r][k]);
            float4 a1 = *reinterpret_cast<const float4*>(&As[r][k + 4]);
            acc0 += a0.x * Wsm[(size_t)(k + 0) * 128 + c];
            acc1 += a0.y * Wsm[(size_t)(k + 1) * 128 + c];
            acc0 += a0.z * Wsm[(size_t)(k + 2) * 128 + c];
            acc1 += a0.w * Wsm[(size_t)(k + 3) * 128 + c];
            acc0 += a1.x * Wsm[(size_t)(k + 4) * 128 + c];
            acc1 += a1.y * Wsm[(size_t)(k + 5) * 128 + c];
            acc0 += a1.z * Wsm[(size_t)(k + 6) * 128 + c];
            acc1 += a1.w * Wsm[(size_t)(k + 7) * 128 + c];
        }
        int row = row0 + r;
        if (row < G_) {
            float v = fmaxf(acc0 + acc1 + bsm[c], 0.f);
            z[(size_t)row * 640 + 512 + c] = v;
        }
    }
}

// ---- final head with fused BNf apply+relu ---------------------------------
__global__ void final_head_bn(const float* __restrict__ f1,
                              const float* __restrict__ scale, const float* __restrict__ shift,
                              const float* __restrict__ Wf2, const float* __restrict__ bf2,
                              float* __restrict__ out, int G_)
{
    int w = (int)(((long long)blockIdx.x * blockDim.x + threadIdx.x) >> 6);
    int lane = threadIdx.x & 63;
    if (w >= G_) return;
    float s = 0.f;
    #pragma unroll
    for (int q = 0; q < 2; ++q) {
        int c = lane + q * 64;
        float v = fmaxf(f1[(size_t)w * 128 + c] * scale[c] + shift[c], 0.f);
        s += v * Wf2[c];
    }
    #pragma unroll
    for (int off = 32; off; off >>= 1) s += __shfl_down(s, off);
    if (lane == 0) out[w] = 1.f / (1.f + __expf(-(s + bf2[0])));
}

__global__ void sentinel(float* __restrict__ out, int n, float v)
{
    int i = blockIdx.x * blockDim.x + threadIdx.x;
    if (i < n) out[i] = v;
}

// ---------------------------------------------------------------------------
extern "C" void kernel_launch(void* const* d_in, const int* in_sizes, int n_in,
                              void* d_out, int out_size, void* d_ws, size_t ws_size,
                              hipStream_t stream)
{
    const float* x    = (const float*)d_in[0];
    const int*   ei   = (const int*)d_in[1];
    const int*   batch= (const int*)d_in[2];
    const float* sfp  = (const float*)d_in[3];
    const float* W1   = (const float*)d_in[4];
    const float* a1s  = (const float*)d_in[5];
    const float* a1d  = (const float*)d_in[6];
    const float* bn1g = (const float*)d_in[8];
    const float* bn1b = (const float*)d_in[9];
    const float* W2   = (const float*)d_in[10];
    const float* a2s  = (const float*)d_in[11];
    const float* a2d  = (const float*)d_in[12];
    const float* bn2g = (const float*)d_in[14];
    const float* bn2b = (const float*)d_in[15];
    const float* Wg   = (const float*)d_in[16];
    const float* bn3g = (const float*)d_in[18];
    const float* bn3b = (const float*)d_in[19];
    const float* Wsm  = (const float*)d_in[20];
    const float* bsm  = (const float*)d_in[21];
    const float* Wf1  = (const float*)d_in[22];
    const float* bnfg = (const float*)d_in[24];
    const float* bnfb = (const float*)d_in[25];
    const float* Wf2  = (const float*)d_in[26];
    const float* bf2  = (const float*)d_in[27];
    float* outp = (float*)d_out;

    const int N    = in_sizes[0] / 64;
    const int E    = in_sizes[1] / 2;
    const int G_   = in_sizes[3] / 128;
    const int Etot = E + N;
    const int* esrc = ei;
    const int* edst = ei + E;
    const int YB = 256;
    const int NB = cdiv(N, 1024);
    const int NYT = cdiv(N, 128);                 // GEMM row tiles
    const int NYT8 = cdiv(NYT, 8) * 8;            // padded for swizzle

    // ---- workspace (fp32-element offsets) ----
    float* ws = (float*)d_ws;
    size_t off = 0;
    float* accA  = ws + off; off += (size_t)N * 256;
    float* h3acc = ws + off; off += (size_t)N * 256;
    unsigned short* g1b   = (unsigned short*)accA;   // [N,512] bf16 L1 GEMM out
    unsigned short* g3b   = (unsigned short*)accA;   // [N,256] bf16 GCN-gather out
    unsigned short* h2all = (unsigned short*)accA;   // [N,1024] bf16 (spans accA+h3acc!)
    unsigned short* R1 = (unsigned short*)(ws + off); off += (size_t)N * 256; // N*512 bf16
    unsigned short* o1n = R1;
    unsigned short* hb  = (unsigned short*)(ws + off); off += (size_t)N * 128; // N*256 bf16
    unsigned short* xb  = (unsigned short*)(ws + off); off += (size_t)N * 32;  // N*64 bf16
    float* alsd = ws + off; off += (size_t)N * 8;
    float* dinv = ws + off; off += N;
    float* bsc = ws + off; off += 1024;
    float* bsh = ws + off; off += 1024;
    // ps/pq: base region (overwrite-style bn_part_bf, YB*512) + 4 atomic
    // regions zeroed once up front: P0 (512), P1 (512), G (256), F (128).
    float* ps  = ws + off; off += (size_t)YB * 1920;
    float* pq  = ws + off; off += (size_t)YB * 1920;
    float* psP0 = ps + (size_t)YB * 512;
    float* psP1 = ps + (size_t)YB * 1024;
    float* psG  = ps + (size_t)YB * 1536;
    float* psF  = ps + (size_t)YB * 1792;
    float* pqP0 = pq + (size_t)YB * 512;
    float* pqP1 = pq + (size_t)YB * 1024;
    float* pqG  = pq + (size_t)YB * 1536;
    float* pqF  = pq + (size_t)YB * 1792;
    float* z   = ws + off; off += (size_t)G_ * 640;
    float* f1  = ws + off; off += (size_t)G_ * 128;
    int* rowptr = (int*)(ws + off); off += (size_t)(N + 1);
    int* colc   = (int*)(ws + off); off += (size_t)Etot;
    int* gptr   = (int*)(ws + off); off += (size_t)(G_ + 1);
    int* bsums  = (int*)(ws + off); off += 256;
    off = (off + 3) & ~(size_t)3;                 // 16B-align the bf16 tables
    unsigned short* vat1 = (unsigned short*)(ws + off); off += 128 * 64 / 2;
    unsigned short* vat2 = (unsigned short*)(ws + off); off += 128 * 512 / 2;
    unsigned short* W1bdt = (unsigned short*)(ws + off); off += 512 * 256 / 2;
    unsigned short* W2t = (unsigned short*)(ws + off); off += 512 * 1024 / 2;
    unsigned short* Wgt = (unsigned short*)(ws + off); off += 1024 * 256 / 2;
    int* cursor = (int*)alsd;   // alias: cursor dead before alsd is written
    size_t need = off * 4;
    if (ws_size < need) {
        sentinel<<<cdiv(out_size, 256), 256, 0, stream>>>(outp, out_size, (float)(ws_size >> 20));
        return;
    }

    const int BLK = 256;
    dim3 blk(BLK);

    // zero the atomic-stats regions ONCE, up front (overlaps prep/CSR work)
    hipMemsetAsync(psP0, 0, (size_t)YB * 1408 * 4, stream);  // P0+P1+G+F contiguous
    hipMemsetAsync(pqP0, 0, (size_t)YB * 1408 * 4, stream);

    // ============ MEGA-PREP (weights, x cast, vat, cursor, gptr) ============
    const int c0 = 512;
    const int c1 = c0 + 2048;
    const int c2 = c1 + 1024;
    const int c3 = c2 + cdiv((long long)N * 16, 256);
    const int c4 = c3 + 64;
    const int c5 = c4 + 512;
    const int c6 = c5 + cdiv(N, 256);
    const int c7 = c6 + cdiv(G_ + 1, 256);
    prep_all<<<c7, blk, 0, stream>>>(W1, W2, Wg, x, a1s, a1d, a2s, a2d, batch,
                                     W1bdt, W2t, Wgt, xb, vat1, vat2,
                                     cursor, gptr, N, G_,
                                     c0, c1, c2, c3, c4, c5, c6);

    // ================= build CSR (dst -> src) ===============================
    hist_dst<<<cdiv(E, BLK), blk, 0, stream>>>(edst, E, cursor);
    scan_blk<<<NB, blk, 0, stream>>>(cursor, rowptr, bsums, N);
    scan_tops<<<1, blk, 0, stream>>>(bsums, rowptr, NB, N);
    scan_add<<<cdiv(N, BLK), blk, 0, stream>>>(rowptr, cursor, bsums, N);
    { int NBsc = cdiv(Etot, BLK);
      csr_scatter_dinv<<<NBsc + cdiv(N, BLK), blk, 0, stream>>>(
          esrc, edst, E, Etot, cursor, colc, rowptr, dinv, N, NBsc); }

    // ====== GAT layer 1, AGGREGATE-FIRST: logits -> agg(x, exp inline) -> GEMM
    logits_valu<<<cdiv(N, 32), blk, 0, stream>>>(xb, vat1, alsd, N, 64);
    gat_agg4_64<<<cdiv((long long)N * 64, BLK), blk, 0, stream>>>(
        rowptr, colc, xb, alsd, hb, N);
    gemm_mfma<<<NYT8 * 4, blk, 0, stream>>>(hb, W1bdt, g1b, N, 256, 256, 256, 512, 4, NYT);
    { dim3 g(1, YB); bn_part_bf<512><<<g, blk, 0, stream>>>(g1b, 512, ps, pq, N, YB); }
    bn_reduce_fin<512><<<8, blk, 0, stream>>>(ps, pq, bn1g, bn1b, bsc, bsh, YB, 1.f / N);
    // fused: relu(bn(g1b)) -> o1n  AND layer-2 logits -> alsd
    bn_apply_logits512<<<cdiv(N, 4), blk, 0, stream>>>(
        g1b, bsc, bsh, vat2, o1n, alsd, N);

    // ======= GAT layer 2: ONE batched GEMM (512 -> 1024), XCD-swizzled =====
    gemm_mfma<<<NYT8 * 8, blk, 0, stream>>>(o1n, W2t, h2all, N, 512, 512, 512, 1024, 8, NYT);
    // R1 (o1n) dead after the GEMM: head-pair gathers (exp + BN-stats fused)
    // -> R1; fin; apply back into h2all column block. Per-site stats regions.
    for (int pr = 0; pr < 2; ++pr) {
        float* pssite = pr ? psP1 : psP0;
        float* pqsite = pr ? pqP1 : pqP0;
        gat_gather512_ex<<<cdiv((long long)N * 64, BLK), blk, 0, stream>>>(
            rowptr, colc, h2all + pr * 512, 1024, alsd, pr, R1, pssite, pqsite, N);
        bn_reduce_fin<512><<<8, blk, 0, stream>>>(pssite, pqsite, bn2g + pr * 512, bn2b + pr * 512,
                                                  bsc + pr * 512, bsh + pr * 512, YB, 1.f / N);
        bn_apply_bfbf<<<cdiv((long long)N * 128, BLK), blk, 0, stream>>>(
            R1, bsc + pr * 512, bsh + pr * 512, h2all + pr * 512, N * 128, 128, 512, 1024);
    }

    // GCN GEMM: K=1024, 2 column blocks, XCD-swizzled (A read ~once)
    gemm_mfma<<<NYT8 * 2, blk, 0, stream>>>(h2all, Wgt, hb, N, 1024, 1024, 1024, 256, 2, NYT);

    // ================= GCN aggregation (BN3 stats fused) ====================
    gcn_gather256<<<cdiv((long long)N * 64, BLK), blk, 0, stream>>>(
        rowptr, colc, hb, dinv, g3b, psG, pqG, N);
    bn_reduce_fin<256><<<4, blk, 0, stream>>>(psG, pqG, bn3g, bn3b, bsc, bsh, YB, 1.f / N);

    // ======== Pooling (BN3+relu fused) + solvent MLP, ONE launch ============
    pool_solv<<<G_ + cdiv(G_, 2), blk, 0, stream>>>(
        g3b, bsc, bsh, gptr, z, G_, sfp, Wsm, bsm);

    // ================= Head (BNf stats fused into the GEMM epilogue) ========
    gemm_small<false><<<cdiv(G_, 2), blk, 0, stream>>>(
        z, Wf1, nullptr, f1, G_, 640, 640, 128, 128, psF, pqF);
    bn_reduce_fin<128><<<2, blk, 0, stream>>>(psF, pqF, bnfg, bnfb, bsc, bsh, YB, 1.f / G_);
    final_head_bn<<<cdiv((long long)G_ * 64, BLK), blk, 0, stream>>>(
        f1, bsc, bsh, Wf2, bf2, outp, G_);
}

// Round 14
// 757.942 us; speedup vs baseline: 1.0131x; 1.0131x over previous
//
#include <hip/hip_runtime.h>
#include <cmath>

#define LEAK 0.2f
#define BN_EPS 1e-5f

static inline int cdiv(long long a, long long b){ return (int)((a + b - 1) / b); }

typedef __attribute__((ext_vector_type(8))) short bf16x8;
typedef __attribute__((ext_vector_type(4))) float f32x4;

// ---- bf16 helpers (manual, RNE) -------------------------------------------
__device__ __forceinline__ float bf2f(unsigned short u){
    return __uint_as_float(((unsigned int)u) << 16);
}
__device__ __forceinline__ unsigned short f2bf(float f){
    unsigned int u = __float_as_uint(f);
    u += 0x7FFFu + ((u >> 16) & 1u);
    return (unsigned short)(u >> 16);
}
__device__ __forceinline__ float edge_ex(float s, float d){
    float t = s + d;
    t = (t >= 0.f) ? t : LEAK * t;
    return __expf(t);
}

// async global->LDS, 16B per lane. LDS dest must be linear: wave-uniform base
// + lane*16 (m104). Source address is per-lane -> swizzle goes on the SOURCE.
#define GLOAD_LDS16(gsrc, ldst) \
    __builtin_amdgcn_global_load_lds( \
        (const __attribute__((address_space(1))) unsigned int*)(gsrc), \
        (__attribute__((address_space(3))) unsigned int*)(ldst), 16, 0, 0)

// ---------------------------------------------------------------------------
// MFMA bf16 GEMM (128x128 tile, BK=64, 4 waves x 4x4 16x16x32 MFMAs).
// m97 staging + BK=64 + both-sides XOR chunk swizzle (R4: 82us, 0 conflicts).
// XCD-aware 1D swizzle. grid.x = 8 * cdiv(NYT,8) * NX.  K % 64 == 0.
// R13: LDS-repack epilogue for coalesced 16B stores (79.5 -> 77.2us).
// ---------------------------------------------------------------------------
__global__ __launch_bounds__(256) void gemm_mfma(
    const unsigned short* __restrict__ A, const unsigned short* __restrict__ Bt,
    unsigned short* __restrict__ D, int M, int K, int lda, int ldb, int ldc,
    int NX, int NYT)
{
    const int id = blockIdx.x;
    const int xcd = id & 7;
    const int j = id >> 3;
    const int bx = j % NX;
    const int by = (j / NX) * 8 + xcd;
    if (by >= NYT) return;

    __shared__ unsigned short As[128 * 64];
    __shared__ unsigned short Bs[128 * 64];
    const int t = threadIdx.x;
    const int row0 = by * 128, col0 = bx * 128;
    const int lane = t & 63, wv = t >> 6;
    const int wm = (wv >> 1) << 6, wn = (wv & 1) << 6;
    const int lm = lane & 15, lq = lane >> 4;

    const int sr  = t >> 3;                       // 0..31
    const int scs = (t & 7) << 3;                 // LDS col in shorts (linear)
    const int gsw = (((t & 7) ^ (sr & 7)) << 3);  // global col in shorts
    const unsigned short* ap[4];
    const unsigned short* bp[4];
    unsigned short* la[4];
    unsigned short* lb[4];
    #pragma unroll
    for (int q = 0; q < 4; ++q) {
        int r = sr + q * 32;
        int gra = row0 + r; if (gra >= M) gra = M - 1;
        ap[q] = A  + (size_t)gra * lda + gsw;
        bp[q] = Bt + (size_t)(col0 + r) * ldb + gsw;
        la[q] = &As[r * 64 + scs];
        lb[q] = &Bs[r * 64 + scs];
    }

    f32x4 acc[4][4] = {};
    const int rx = lm & 7;                        // row&7 for this lane's reads

    for (int k0 = 0; k0 < K; k0 += 64) {
        #pragma unroll
        for (int q = 0; q < 4; ++q) {
            GLOAD_LDS16(ap[q] + k0, la[q]);
            GLOAD_LDS16(bp[q] + k0, lb[q]);
        }
        __syncthreads();

        #pragma unroll
        for (int kk = 0; kk < 2; ++kk) {
            const int ck = (((kk << 2) + lq) ^ rx) << 3;   // swizzled chunk col
            bf16x8 af[4], bfr[4];
            #pragma unroll
            for (int mi = 0; mi < 4; ++mi)
                af[mi] = *(const bf16x8*)&As[(wm + mi * 16 + lm) * 64 + ck];
            #pragma unroll
            for (int ni = 0; ni < 4; ++ni)
                bfr[ni] = *(const bf16x8*)&Bs[(wn + ni * 16 + lm) * 64 + ck];
            #pragma unroll
            for (int mi = 0; mi < 4; ++mi)
                #pragma unroll
                for (int ni = 0; ni < 4; ++ni)
                    acc[mi][ni] = __builtin_amdgcn_mfma_f32_16x16x32_bf16(
                        af[mi], bfr[ni], acc[mi][ni], 0, 0, 0);
        }
        __syncthreads();
    }
    // K-loop's trailing barrier: all ds_reads drained -> As/Bs reusable.

    // ---- epilogue: repack C tile via LDS for coalesced 16B stores ----------
    #pragma unroll
    for (int mi = 0; mi < 4; ++mi) {
        #pragma unroll
        for (int r = 0; r < 4; ++r) {
            int row = wm + mi * 16 + lq * 4 + r;
            unsigned short* base = (row < 64) ? &As[row * 128] : &Bs[(row - 64) * 128];
            #pragma unroll
            for (int ni = 0; ni < 4; ++ni) {
                int col = (wn + ni * 16 + lm) ^ (lq << 4);
                base[col] = f2bf(acc[mi][ni][r]);
            }
        }
    }
    __syncthreads();
    #pragma unroll
    for (int i = 0; i < 8; ++i) {
        int idx = i * 256 + t;                 // 0..2047: 128 rows x 16 chunks
        int row = idx >> 4;
        int lqr = (row >> 2) & 3;
        int c8l = (idx & 15) << 3;             // logical chunk col
        int c8p = c8l ^ (lqr << 4);            // physical (swizzled) col
        int grow = row0 + row;
        if (grow < M) {
            const unsigned short* base = (row < 64) ? &As[row * 128] : &Bs[(row - 64) * 128];
            bf16x8 v = *(const bf16x8*)&base[c8p];
            *(bf16x8*)(D + (size_t)grow * ldc + col0 + c8l) = v;
        }
    }
}

// ---------------------------------------------------------------------------
// Logits: C[M,8] = A[M,K] @ vat[8,K]^T (used for K=64, layer 1).
// ---------------------------------------------------------------------------
__global__ __launch_bounds__(256) void logits_valu(
    const unsigned short* __restrict__ A, const unsigned short* __restrict__ vat,
    float* __restrict__ C, int M, int K)
{
    __shared__ unsigned short vs[8 * 512];
    const int t = threadIdx.x;
    for (int i = t; i < K; i += 256)
        *(bf16x8*)&vs[i * 8] = *(const bf16x8*)(vat + (size_t)i * 8);
    __syncthreads();

    const int lane = t & 63;
    const int w = blockIdx.x * 4 + (t >> 6);
    const int Gl = K >> 3;                     // lanes per row (8 or 64)
    const int rpw = 64 / Gl;                   // rows per wave
    const int sub = lane / Gl;
    const int li = lane - sub * Gl;
    long long row = (long long)w * rpw + sub;
    if (row >= M) return;

    bf16x8 hv = *(const bf16x8*)(A + row * K + li * 8);
    float hf[8];
    #pragma unroll
    for (int j = 0; j < 8; ++j) hf[j] = bf2f((unsigned short)hv[j]);

    float s[8];
    #pragma unroll
    for (int o = 0; o < 8; ++o) {
        bf16x8 v = *(const bf16x8*)&vs[o * K + li * 8];
        float acc = 0.f;
        #pragma unroll
        for (int j = 0; j < 8; ++j) acc += hf[j] * bf2f((unsigned short)v[j]);
        s[o] = acc;
    }
    for (int off = Gl >> 1; off; off >>= 1) {
        #pragma unroll
        for (int o = 0; o < 8; ++o) s[o] += __shfl_xor(s[o], off);
    }
    #pragma unroll
    for (int o = 0; o < 8; ++o)
        if (li == o) C[row * 8 + o] = s[o];
}

// ---------------------------------------------------------------------------
// FUSED: relu(bn(g1b)) -> o1n bf16  AND  layer-2 logits (K=512).
// R14: PERSISTENT blocks -- vat2 staged ONCE per block, grid-stride row loop
// (was 12500 blocks x 8KB staging = 100MB redundant vat2 reads; now 2048).
// No barriers inside the loop -> divergent exit safe.
// ---------------------------------------------------------------------------
__global__ __launch_bounds__(256) void bn_apply_logits512(
    const unsigned short* __restrict__ g1b,
    const float* __restrict__ scale, const float* __restrict__ shift,
    const unsigned short* __restrict__ vat,
    unsigned short* __restrict__ o1n, float* __restrict__ C, int M, int nblk)
{
    __shared__ unsigned short vs[8 * 512];
    const int t = threadIdx.x;
    for (int i = t; i < 512; i += 256)
        *(bf16x8*)&vs[i * 8] = *(const bf16x8*)(vat + (size_t)i * 8);
    __syncthreads();

    const int lane = t & 63;
    const long long stride = (long long)nblk * 4;
    for (long long row = (long long)blockIdx.x * 4 + (t >> 6); row < M; row += stride) {
        bf16x8 u = *(const bf16x8*)(g1b + row * 512 + lane * 8);
        float4 sc0 = *(const float4*)(scale + lane * 8);
        float4 sc1 = *(const float4*)(scale + lane * 8 + 4);
        float4 sh0 = *(const float4*)(shift + lane * 8);
        float4 sh1 = *(const float4*)(shift + lane * 8 + 4);
        float hf[8];
        hf[0] = fmaxf(bf2f((unsigned short)u[0]) * sc0.x + sh0.x, 0.f);
        hf[1] = fmaxf(bf2f((unsigned short)u[1]) * sc0.y + sh0.y, 0.f);
        hf[2] = fmaxf(bf2f((unsigned short)u[2]) * sc0.z + sh0.z, 0.f);
        hf[3] = fmaxf(bf2f((unsigned short)u[3]) * sc0.w + sh0.w, 0.f);
        hf[4] = fmaxf(bf2f((unsigned short)u[4]) * sc1.x + sh1.x, 0.f);
        hf[5] = fmaxf(bf2f((unsigned short)u[5]) * sc1.y + sh1.y, 0.f);
        hf[6] = fmaxf(bf2f((unsigned short)u[6]) * sc1.z + sh1.z, 0.f);
        hf[7] = fmaxf(bf2f((unsigned short)u[7]) * sc1.w + sh1.w, 0.f);
        bf16x8 o;
        #pragma unroll
        for (int j = 0; j < 8; ++j) o[j] = (short)f2bf(hf[j]);
        *(bf16x8*)(o1n + row * 512 + lane * 8) = o;

        float s[8];
        #pragma unroll
        for (int oo = 0; oo < 8; ++oo) {
            bf16x8 v = *(const bf16x8*)&vs[oo * 512 + lane * 8];
            float acc = 0.f;
            #pragma unroll
            for (int j = 0; j < 8; ++j) acc += hf[j] * bf2f((unsigned short)v[j]);
            s[oo] = acc;
        }
        #pragma unroll
        for (int off = 32; off; off >>= 1) {
            #pragma unroll
            for (int oo = 0; oo < 8; ++oo) s[oo] += __shfl_xor(s[oo], off);
        }
        #pragma unroll
        for (int oo = 0; oo < 8; ++oo)
            if (lane == oo) C[row * 8 + oo] = s[oo];
    }
}

// ---------------------------------------------------------------------------
// MEGA-PREP: all weight conversions + x cast + vat + cursor init + group LB
// in ONE launch, segmented by blockIdx ranges (each branch is block-uniform).
// ---------------------------------------------------------------------------
__global__ __launch_bounds__(256) void prep_all(
    const float* __restrict__ W1, const float* __restrict__ W2,
    const float* __restrict__ Wg, const float* __restrict__ x,
    const float* __restrict__ a1s, const float* __restrict__ a1d,
    const float* __restrict__ a2s, const float* __restrict__ a2d,
    const int* __restrict__ batch,
    unsigned short* __restrict__ W1bdt, unsigned short* __restrict__ W2t,
    unsigned short* __restrict__ Wgt, unsigned short* __restrict__ xb,
    unsigned short* __restrict__ vat1, unsigned short* __restrict__ vat2,
    int* __restrict__ cursor, int* __restrict__ gptr,
    int N, int G_,
    int c0, int c1, int c2, int c3, int c4, int c5, int c6)
{
    const int t = threadIdx.x;
    const int bid = blockIdx.x;
    if (bid < c0) {
        int i = bid * 256 + t;                 // exactly 512*256
        int o = i >> 8, k = i & 255;
        unsigned short v = 0;
        if ((k >> 6) == (o >> 7)) v = f2bf(W1[(size_t)(k & 63) * 512 + o]);
        W1bdt[i] = v;
    } else if (bid < c1) {
        int i = (bid - c0) * 256 + t;          // exactly 512*1024
        int k = i >> 10, n = i & 1023;
        W2t[(size_t)n * 512 + k] = f2bf(W2[i]);
    } else if (bid < c2) {
        int i = (bid - c1) * 256 + t;          // exactly 1024*256
        int k = i >> 8, n = i & 255;
        Wgt[(size_t)n * 1024 + k] = f2bf(Wg[i]);
    } else if (bid < c3) {
        int i = (bid - c2) * 256 + t;
        if (i < N * 16) {
            float4 v = *reinterpret_cast<const float4*>(x + (size_t)i * 4);
            ushort4 o = { f2bf(v.x), f2bf(v.y), f2bf(v.z), f2bf(v.w) };
            *reinterpret_cast<ushort4*>(xb + (size_t)i * 4) = o;
        }
    } else if (bid < c4) {
        int w = (((bid - c3) * 256 + t) >> 6);
        int lane = t & 63;
        int k = w >> 2, h = w & 3;
        const float* wp = W1 + (size_t)k * 512 + h * 128;
        const float* as = a1s + h * 128;
        const float* ad = a1d + h * 128;
        float s = 0.f, d = 0.f;
        for (int c = lane; c < 128; c += 64) {
            float v = wp[c];
            s += v * as[c];
            d += v * ad[c];
        }
        #pragma unroll
        for (int off = 32; off; off >>= 1) {
            s += __shfl_down(s, off);
            d += __shfl_down(d, off);
        }
        if (lane == 0) {
            vat1[(size_t)h * 64 + k] = f2bf(s);
            vat1[(size_t)(4 + h) * 64 + k] = f2bf(d);
        }
    } else if (bid < c5) {
        int w = (((bid - c4) * 256 + t) >> 6);
        int lane = t & 63;
        int k = w >> 2, h = w & 3;
        const float* wp = W2 + (size_t)k * 1024 + h * 256;
        const float* as = a2s + h * 256;
        const float* ad = a2d + h * 256;
        float s = 0.f, d = 0.f;
        for (int c = lane; c < 256; c += 64) {
            float v = wp[c];
            s += v * as[c];
            d += v * ad[c];
        }
        #pragma unroll
        for (int off = 32; off; off >>= 1) {
            s += __shfl_down(s, off);
            d += __shfl_down(d, off);
        }
        if (lane == 0) {
            vat2[(size_t)h * 512 + k] = f2bf(s);
            vat2[(size_t)(4 + h) * 512 + k] = f2bf(d);
        }
    } else if (bid < c6) {
        int i = (bid - c5) * 256 + t;
        if (i < N) cursor[i] = 1;
    } else {
        int g = (bid - c6) * 256 + t;
        if (g > G_) return;
        if (g == G_) { gptr[G_] = N; return; }
        int lo = 0, hi = N;
        while (lo < hi) { int mid = (lo + hi) >> 1; if (batch[mid] < g) lo = mid + 1; else hi = mid; }
        gptr[g] = lo;
    }
}

// ---------------------------------------------------------------------------
// Small-M fp32 GEMM, Nc = 128: one output/thread, 2 rows/block, A in LDS.
// Optional fused BN stats (per-thread atomicAdd; cheap -- no extra sync).
// ---------------------------------------------------------------------------
template<bool RELU>
__global__ __launch_bounds__(256) void gemm_small(
    const float* __restrict__ A, const float* __restrict__ B,
    const float* __restrict__ bias, float* __restrict__ C,
    int M, int K, int lda, int ldb, int ldc,
    float* __restrict__ ps, float* __restrict__ pq)
{
    __shared__ float As[2][640];
    const int t = threadIdx.x;
    const int r = t >> 7, c = t & 127;
    const int row0 = blockIdx.x * 2;
    for (int i = t; i < 2 * K; i += 256) {
        int rr = i / K, kk = i - rr * K;
        int gr = row0 + rr;
        As[rr][kk] = (gr < M) ? A[(size_t)gr * lda + kk] : 0.f;
    }
    __syncthreads();
    float acc0 = 0.f, acc1 = 0.f;
    for (int k = 0; k < K; k += 8) {
        float4 a0 = *reinterpret_cast<const float4*>(&As[r][k]);
        float4 a1 = *reinterpret_cast<const float4*>(&As[r][k + 4]);
        acc0 += a0.x * B[(size_t)(k + 0) * ldb + c];
        acc1 += a0.y * B[(size_t)(k + 1) * ldb + c];
        acc0 += a0.z * B[(size_t)(k + 2) * ldb + c];
        acc1 += a0.w * B[(size_t)(k + 3) * ldb + c];
        acc0 += a1.x * B[(size_t)(k + 4) * ldb + c];
        acc1 += a1.y * B[(size_t)(k + 5) * ldb + c];
        acc0 += a1.z * B[(size_t)(k + 6) * ldb + c];
        acc1 += a1.w * B[(size_t)(k + 7) * ldb + c];
    }
    int row = row0 + r;
    if (row < M) {
        float v = acc0 + acc1;
        if (bias) v += bias[c];
        if (RELU) v = fmaxf(v, 0.f);
        C[(size_t)row * ldc + c] = v;
        if (ps) {
            size_t slot = (size_t)(blockIdx.x & 255) * 128 + c;
            atomicAdd(&ps[slot], v);
            atomicAdd(&pq[slot], v * v);
        }
    }
}

// ============================ CSR build ====================================
__device__ __forceinline__ int e_src(const int* es, int E, int k){ return k < E ? es[k] : k - E; }
__device__ __forceinline__ int e_dst(const int* ed, int E, int k){ return k < E ? ed[k] : k - E; }

__global__ void hist_dst(const int* __restrict__ ed, int E, int* __restrict__ cnt)
{
    int k = blockIdx.x * blockDim.x + threadIdx.x;
    if (k < E) atomicAdd(&cnt[ed[k]], 1);
}

__global__ __launch_bounds__(256) void scan_blk(const int* __restrict__ cnt,
                                                int* __restrict__ rowptr,
                                                int* __restrict__ bsums, int n)
{
    __shared__ int ts[256];
    const int t = threadIdx.x;
    const int i0 = blockIdx.x * 1024 + t * 4;
    int4 v = {0, 0, 0, 0};
    if (i0 + 3 < n) v = *reinterpret_cast<const int4*>(cnt + i0);
    else {
        if (i0 + 0 < n) v.x = cnt[i0 + 0];
        if (i0 + 1 < n) v.y = cnt[i0 + 1];
        if (i0 + 2 < n) v.z = cnt[i0 + 2];
        if (i0 + 3 < n) v.w = cnt[i0 + 3];
    }
    int lsum = v.x + v.y + v.z + v.w;
    ts[t] = lsum;
    __syncthreads();
    #pragma unroll
    for (int off = 1; off < 256; off <<= 1) {
        int u = (t >= off) ? ts[t - off] : 0;
        __syncthreads();
        ts[t] += u;
        __syncthreads();
    }
    int excl = ts[t] - lsum;
    if (i0 + 0 < n) rowptr[i0 + 0] = excl;
    if (i0 + 1 < n) rowptr[i0 + 1] = excl + v.x;
    if (i0 + 2 < n) rowptr[i0 + 2] = excl + v.x + v.y;
    if (i0 + 3 < n) rowptr[i0 + 3] = excl + v.x + v.y + v.z;
    if (t == 255) bsums[blockIdx.x] = ts[255];
}

__global__ __launch_bounds__(256) void scan_tops(int* __restrict__ bsums,
                                                 int* __restrict__ rowptr, int nb, int n)
{
    __shared__ int ts[256];
    const int t = threadIdx.x;
    int v = (t < nb) ? bsums[t] : 0;
    ts[t] = v;
    __syncthreads();
    #pragma unroll
    for (int off = 1; off < 256; off <<= 1) {
        int u = (t >= off) ? ts[t - off] : 0;
        __syncthreads();
        ts[t] += u;
        __syncthreads();
    }
    if (t < nb) bsums[t] = ts[t] - v;
    if (t == 255) rowptr[n] = ts[255];
}

__global__ void scan_add(int* __restrict__ rowptr, int* __restrict__ cursor,
                         const int* __restrict__ bsums, int n)
{
    int i = blockIdx.x * blockDim.x + threadIdx.x;
    if (i >= n) return;
    int r = rowptr[i] + bsums[i >> 10];
    rowptr[i] = r;
    cursor[i] = r;
}

// scatter (no dstarr) + dinv, one launch (blockIdx split)
__global__ void csr_scatter_dinv(const int* __restrict__ es, const int* __restrict__ ed,
                                 int E, int Etot, int* __restrict__ cursor,
                                 int* __restrict__ col,
                                 const int* __restrict__ rowptr,
                                 float* __restrict__ dinv, int N, int NBsc)
{
    const int bid = blockIdx.x;
    const int t = threadIdx.x;
    if (bid < NBsc) {
        int k = bid * 256 + t;
        if (k >= Etot) return;
        int sn = e_src(es, E, k), dn = e_dst(ed, E, k);
        int pos = atomicAdd(&cursor[dn], 1);
        col[pos] = sn;
    } else {
        int i = (bid - NBsc) * 256 + t;
        if (i < N) dinv[i] = rsqrtf(fmaxf((float)(rowptr[i + 1] - rowptr[i]), 1.f));
    }
}

// ====== layer-1 AGGREGATE-FIRST gather, exp fused, 2-edge ILP unroll =======
__global__ void gat_agg4_64(const int* __restrict__ rowptr, const int* __restrict__ col,
                            const unsigned short* __restrict__ xb,
                            const float* __restrict__ alsd,
                            unsigned short* __restrict__ agg, int N)
{
    int w = (int)(((long long)blockIdx.x * blockDim.x + threadIdx.x) >> 6);
    int lane = threadIdx.x & 63;
    if (w >= N) return;
    float4 dt = *reinterpret_cast<const float4*>(alsd + (size_t)w * 8 + 4);
    int r0 = rowptr[w], r1 = rowptr[w + 1];
    float a0 = 0.f, a1 = 0.f, a2 = 0.f, a3 = 0.f;
    float s0 = 0.f, s1 = 0.f, s2 = 0.f, s3 = 0.f;
    int e = r0;
    for (; e + 1 < r1; e += 2) {
        int snA = col[e], snB = col[e + 1];
        float4 stA = *reinterpret_cast<const float4*>(alsd + (size_t)snA * 8);
        float4 stB = *reinterpret_cast<const float4*>(alsd + (size_t)snB * 8);
        float xA = bf2f(xb[(size_t)snA * 64 + lane]);
        float xB = bf2f(xb[(size_t)snB * 64 + lane]);
        float eA0 = edge_ex(stA.x, dt.x), eB0 = edge_ex(stB.x, dt.x);
        float eA1 = edge_ex(stA.y, dt.y), eB1 = edge_ex(stB.y, dt.y);
        float eA2 = edge_ex(stA.z, dt.z), eB2 = edge_ex(stB.z, dt.z);
        float eA3 = edge_ex(stA.w, dt.w), eB3 = edge_ex(stB.w, dt.w);
        a0 += eA0 * xA + eB0 * xB;  s0 += eA0 + eB0;
        a1 += eA1 * xA + eB1 * xB;  s1 += eA1 + eB1;
        a2 += eA2 * xA + eB2 * xB;  s2 += eA2 + eB2;
        a3 += eA3 * xA + eB3 * xB;  s3 += eA3 + eB3;
    }
    if (e < r1) {
        int sn = col[e];
        float4 st = *reinterpret_cast<const float4*>(alsd + (size_t)sn * 8);
        float xA = bf2f(xb[(size_t)sn * 64 + lane]);
        float e0 = edge_ex(st.x, dt.x);
        float e1 = edge_ex(st.y, dt.y);
        float e2 = edge_ex(st.z, dt.z);
        float e3 = edge_ex(st.w, dt.w);
        a0 += e0 * xA; s0 += e0;
        a1 += e1 * xA; s1 += e1;
        a2 += e2 * xA; s2 += e2;
        a3 += e3 * xA; s3 += e3;
    }
    unsigned short* op = agg + (size_t)w * 256 + lane;
    op[0]   = f2bf(a0 / fmaxf(s0, 1e-16f));
    op[64]  = f2bf(a1 / fmaxf(s1, 1e-16f));
    op[128] = f2bf(a2 / fmaxf(s2, 1e-16f));
    op[192] = f2bf(a3 / fmaxf(s3, 1e-16f));
}

// ====== layer-2 gather, TWO heads per pass, exp fused, FUSED BN STATS,
// ====== 2-edge ILP unroll. ps/pq per-site regions, zeroed once up front. ===
__global__ __launch_bounds__(256) void gat_gather512_ex(
    const int* __restrict__ rowptr, const int* __restrict__ col,
    const unsigned short* __restrict__ h, int ldh,
    const float* __restrict__ alsd, int pr,
    unsigned short* __restrict__ out,
    float* __restrict__ ps, float* __restrict__ pq, int N)
{
    const int t = threadIdx.x;
    const int lane = t & 63;
    const int wv = t >> 6;
    int w = (int)(((long long)blockIdx.x * 256 + t) >> 6);
    const bool valid = (w < N);

    float v0=0.f,v1=0.f,v2=0.f,v3=0.f;      // head slot 0 normalized values
    float u0=0.f,u1=0.f,u2=0.f,u3=0.f;      // head slot 1
    if (valid) {
        float2 dt = *reinterpret_cast<const float2*>(alsd + (size_t)w * 8 + 4 + 2 * pr);
        int r0 = rowptr[w], r1 = rowptr[w + 1];
        float s0 = 0.f, s1 = 0.f;
        float a00=0.f,a01=0.f,a02=0.f,a03=0.f;
        float a10=0.f,a11=0.f,a12=0.f,a13=0.f;
        int e = r0;
        for (; e + 1 < r1; e += 2) {
            int snA = col[e], snB = col[e + 1];
            float2 stA = *reinterpret_cast<const float2*>(alsd + (size_t)snA * 8 + 2 * pr);
            float2 stB = *reinterpret_cast<const float2*>(alsd + (size_t)snB * 8 + 2 * pr);
            const unsigned short* pA = h + (size_t)snA * ldh + lane * 4;
            const unsigned short* pB = h + (size_t)snB * ldh + lane * 4;
            ushort4 hA0 = *reinterpret_cast<const ushort4*>(pA);
            ushort4 hA1 = *reinterpret_cast<const ushort4*>(pA + 256);
            ushort4 hB0 = *reinterpret_cast<const ushort4*>(pB);
            ushort4 hB1 = *reinterpret_cast<const ushort4*>(pB + 256);
            float eA0 = edge_ex(stA.x, dt.x), eB0 = edge_ex(stB.x, dt.x);
            float eA1 = edge_ex(stA.y, dt.y), eB1 = edge_ex(stB.y, dt.y);
            s0 += eA0 + eB0; s1 += eA1 + eB1;
            a00 += bf2f(hA0.x) * eA0 + bf2f(hB0.x) * eB0;
            a01 += bf2f(hA0.y) * eA0 + bf2f(hB0.y) * eB0;
            a02 += bf2f(hA0.z) * eA0 + bf2f(hB0.z) * eB0;
            a03 += bf2f(hA0.w) * eA0 + bf2f(hB0.w) * eB0;
            a10 += bf2f(hA1.x) * eA1 + bf2f(hB1.x) * eB1;
            a11 += bf2f(hA1.y) * eA1 + bf2f(hB1.y) * eB1;
            a12 += bf2f(hA1.z) * eA1 + bf2f(hB1.z) * eB1;
            a13 += bf2f(hA1.w) * eA1 + bf2f(hB1.w) * eB1;
        }
        if (e < r1) {
            int sn = col[e];
            float2 st = *reinterpret_cast<const float2*>(alsd + (size_t)sn * 8 + 2 * pr);
            float e0 = edge_ex(st.x, dt.x);
            float e1 = edge_ex(st.y, dt.y);
            const unsigned short* p = h + (size_t)sn * ldh + lane * 4;
            ushort4 h0 = *reinterpret_cast<const ushort4*>(p);
            ushort4 h1 = *reinterpret_cast<const ushort4*>(p + 256);
            s0 += e0; s1 += e1;
            a00 += bf2f(h0.x) * e0; a01 += bf2f(h0.y) * e0;
            a02 += bf2f(h0.z) * e0; a03 += bf2f(h0.w) * e0;
            a10 += bf2f(h1.x) * e1; a11 += bf2f(h1.y) * e1;
            a12 += bf2f(h1.z) * e1; a13 += bf2f(h1.w) * e1;
        }
        float i0 = 1.f / fmaxf(s0, 1e-16f);
        float i1 = 1.f / fmaxf(s1, 1e-16f);
        v0 = a00*i0; v1 = a01*i0; v2 = a02*i0; v3 = a03*i0;
        u0 = a10*i1; u1 = a11*i1; u2 = a12*i1; u3 = a13*i1;
        ushort4 o0 = { f2bf(v0), f2bf(v1), f2bf(v2), f2bf(v3) };
        ushort4 o1 = { f2bf(u0), f2bf(u1), f2bf(u2), f2bf(u3) };
        unsigned short* op = out + (size_t)w * 512 + lane * 4;
        *reinterpret_cast<ushort4*>(op)       = o0;
        *reinterpret_cast<ushort4*>(op + 256) = o1;
    }

    __shared__ float ls[4][512];
    __shared__ float lq[4][512];
    int c0 = lane * 4;
    ls[wv][c0+0]=v0; ls[wv][c0+1]=v1; ls[wv][c0+2]=v2; ls[wv][c0+3]=v3;
    ls[wv][256+c0+0]=u0; ls[wv][256+c0+1]=u1; ls[wv][256+c0+2]=u2; ls[wv][256+c0+3]=u3;
    lq[wv][c0+0]=v0*v0; lq[wv][c0+1]=v1*v1; lq[wv][c0+2]=v2*v2; lq[wv][c0+3]=v3*v3;
    lq[wv][256+c0+0]=u0*u0; lq[wv][256+c0+1]=u1*u1; lq[wv][256+c0+2]=u2*u2; lq[wv][256+c0+3]=u3*u3;
    __syncthreads();
    const size_t slot = (size_t)(blockIdx.x & 255) * 512;
    #pragma unroll
    for (int c = t; c < 512; c += 256) {
        float s = ls[0][c] + ls[1][c] + ls[2][c] + ls[3][c];
        float q = lq[0][c] + lq[1][c] + lq[2][c] + lq[3][c];
        atomicAdd(&ps[slot + c], s);
        atomicAdd(&pq[slot + c], q);
    }
}

// ====== GCN gather (C=256), FUSED BN STATS =================================
__global__ __launch_bounds__(256) void gcn_gather256(
    const int* __restrict__ rowptr, const int* __restrict__ col,
    const unsigned short* __restrict__ h,
    const float* __restrict__ dinv,
    unsigned short* __restrict__ out,
    float* __restrict__ ps, float* __restrict__ pq, int N)
{
    const int t = threadIdx.x;
    const int lane = t & 63;
    const int wv = t >> 6;
    int w = (int)(((long long)blockIdx.x * 256 + t) >> 6);
    const bool valid = (w < N);

    float v0=0.f,v1=0.f,v2=0.f,v3=0.f;
    if (valid) {
        int r0 = rowptr[w], r1 = rowptr[w + 1];
        float a0 = 0.f, a1 = 0.f, a2 = 0.f, a3 = 0.f;
        int e = r0;
        for (; e + 1 < r1; e += 2) {
            int sn0 = col[e], sn1 = col[e + 1];
            float w0 = dinv[sn0], w1 = dinv[sn1];
            ushort4 hv0 = *reinterpret_cast<const ushort4*>(h + (size_t)sn0 * 256 + lane * 4);
            ushort4 hv1 = *reinterpret_cast<const ushort4*>(h + (size_t)sn1 * 256 + lane * 4);
            a0 += bf2f(hv0.x) * w0 + bf2f(hv1.x) * w1;
            a1 += bf2f(hv0.y) * w0 + bf2f(hv1.y) * w1;
            a2 += bf2f(hv0.z) * w0 + bf2f(hv1.z) * w1;
            a3 += bf2f(hv0.w) * w0 + bf2f(hv1.w) * w1;
        }
        if (e < r1) {
            int sn = col[e];
            float wv2 = dinv[sn];
            ushort4 hv = *reinterpret_cast<const ushort4*>(h + (size_t)sn * 256 + lane * 4);
            a0 += bf2f(hv.x) * wv2; a1 += bf2f(hv.y) * wv2;
            a2 += bf2f(hv.z) * wv2; a3 += bf2f(hv.w) * wv2;
        }
        float dn = dinv[w];
        v0 = a0 * dn; v1 = a1 * dn; v2 = a2 * dn; v3 = a3 * dn;
        ushort4 o = { f2bf(v0), f2bf(v1), f2bf(v2), f2bf(v3) };
        *reinterpret_cast<ushort4*>(out + (size_t)w * 256 + lane * 4) = o;
    }

    __shared__ float ls[4][256];
    __shared__ float lq[4][256];
    int c0 = lane * 4;
    ls[wv][c0+0]=v0; ls[wv][c0+1]=v1; ls[wv][c0+2]=v2; ls[wv][c0+3]=v3;
    lq[wv][c0+0]=v0*v0; lq[wv][c0+1]=v1*v1; lq[wv][c0+2]=v2*v2; lq[wv][c0+3]=v3*v3;
    __syncthreads();
    const size_t slot = (size_t)(blockIdx.x & 255) * 256;
    if (t < 256) {
        int c = t;
        float s = ls[0][c] + ls[1][c] + ls[2][c] + ls[3][c];
        float q = lq[0][c] + lq[1][c] + lq[2][c] + lq[3][c];
        atomicAdd(&ps[slot + c], s);
        atomicAdd(&pq[slot + c], q);
    }
}

// ---- BN stats, bf16 input with row stride ldx ------------------------------
template<int D>
__global__ __launch_bounds__(256) void bn_part_bf(
    const unsigned short* __restrict__ x, int ldx,
    float* __restrict__ ps, float* __restrict__ pq, int M, int Y)
{
    constexpr int DG = D / 4;
    constexpr int P  = 256 / DG;
    const int t = threadIdx.x;
    const int cg = t % DG, ph = t / DG;
    const int y = blockIdx.y;
    const int rows_per = (M + Y - 1) / Y;
    const int r0 = y * rows_per;
    const int r1 = min(r0 + rows_per, M);
    float s0=0,s1=0,s2=0,s3=0,q0=0,q1=0,q2=0,q3=0;
    for (int r = r0 + ph; r < r1; r += P) {
        ushort4 u = *reinterpret_cast<const ushort4*>(x + (size_t)r * ldx + cg * 4);
        float vx = bf2f(u.x), vy = bf2f(u.y), vz = bf2f(u.z), vw = bf2f(u.w);
        s0+=vx; s1+=vy; s2+=vz; s3+=vw;
        q0+=vx*vx; q1+=vy*vy; q2+=vz*vz; q3+=vw*vw;
    }
    __shared__ float ls[P][D];
    __shared__ float lq[P][D];
    ls[ph][cg*4+0]=s0; ls[ph][cg*4+1]=s1; ls[ph][cg*4+2]=s2; ls[ph][cg*4+3]=s3;
    lq[ph][cg*4+0]=q0; lq[ph][cg*4+1]=q1; lq[ph][cg*4+2]=q2; lq[ph][cg*4+3]=q3;
    __syncthreads();
    if (ph == 0) {
        #pragma unroll
        for (int j = 0; j < 4; ++j) {
            float ss = 0.f, qq = 0.f;
            #pragma unroll
            for (int p = 0; p < P; ++p) { ss += ls[p][cg*4+j]; qq += lq[p][cg*4+j]; }
            ps[(size_t)y * D + cg*4 + j] = ss;
            pq[(size_t)y * D + cg*4 + j] = qq;
        }
    }
}

// ---- BN finalize: PARALLEL over column groups (grid.x = D/64) -------------
template<int D>
__global__ __launch_bounds__(256) void bn_reduce_fin(
    const float* __restrict__ ps, const float* __restrict__ pq,
    const float* __restrict__ g, const float* __restrict__ b,
    float* __restrict__ scale, float* __restrict__ shift, int Y, float invM)
{
    const int t = threadIdx.x;
    const int cl = t & 63;
    const int c = blockIdx.x * 64 + cl;
    const int ph = t >> 6;                 // 0..3
    float s = 0.f, q = 0.f;
    for (int y = ph; y < Y; y += 4) {
        s += ps[(size_t)y * D + c];
        q += pq[(size_t)y * D + c];
    }
    __shared__ float ls[4][64];
    __shared__ float lq[4][64];
    ls[ph][cl] = s; lq[ph][cl] = q;
    __syncthreads();
    if (ph == 0) {
        s = ls[0][cl] + ls[1][cl] + ls[2][cl] + ls[3][cl];
        q = lq[0][cl] + lq[1][cl] + lq[2][cl] + lq[3][cl];
        float mu = s * invM;
        float var = q * invM - mu * mu;
        float rs = rsqrtf(var + BN_EPS) * g[c];
        scale[c] = rs;
        shift[c] = b[c] - mu * rs;
    }
}

// relu(bn(x)): bf16 in (row stride ldx) -> bf16 out (row stride ldd)
__global__ void bn_apply_bfbf(const unsigned short* __restrict__ x,
                              const float* __restrict__ scale, const float* __restrict__ shift,
                              unsigned short* __restrict__ dst, int total4, int Cb4,
                              int ldx, int ldd)
{
    int i = blockIdx.x * blockDim.x + threadIdx.x;
    if (i >= total4) return;
    int r = i / Cb4, c4 = (i - r * Cb4) * 4;
    ushort4 u = *reinterpret_cast<const ushort4*>(x + (size_t)r * ldx + c4);
    float4 sc = *reinterpret_cast<const float4*>(scale + c4);
    float4 sh = *reinterpret_cast<const float4*>(shift + c4);
    ushort4 o;
    o.x = f2bf(fmaxf(bf2f(u.x) * sc.x + sh.x, 0.f));
    o.y = f2bf(fmaxf(bf2f(u.y) * sc.y + sh.y, 0.f));
    o.z = f2bf(fmaxf(bf2f(u.z) * sc.z + sh.z, 0.f));
    o.w = f2bf(fmaxf(bf2f(u.w) * sc.w + sh.w, 0.f));
    *reinterpret_cast<ushort4*>(dst + (size_t)r * ldd + c4) = o;
}

// ---- Pooling (BN3+relu fused) AND solvent MLP, one launch (blockIdx split) -
__global__ __launch_bounds__(256) void pool_solv(
    const unsigned short* __restrict__ h,
    const float* __restrict__ scale, const float* __restrict__ shift,
    const int* __restrict__ gptr, float* __restrict__ z, int G_,
    const float* __restrict__ sfp, const float* __restrict__ Wsm,
    const float* __restrict__ bsm)
{
    __shared__ float As[2][640];
    const int t = threadIdx.x;
    const int bid = blockIdx.x;
    if (bid < G_) {
        // ---- pooling with fused BN3 apply+relu (2-row ILP) ----
        int g = bid;
        int c = t;
        int r0 = gptr[g], r1 = gptr[g + 1];
        float sc = scale[c], sh = shift[c];
        float s = 0.f, m = 0.f;
        int i = r0;
        for (; i + 1 < r1; i += 2) {
            float v0 = fmaxf(bf2f(h[(size_t)i * 256 + c]) * sc + sh, 0.f);
            float v1 = fmaxf(bf2f(h[(size_t)(i + 1) * 256 + c]) * sc + sh, 0.f);
            s += v0 + v1;
            m = fmaxf(m, fmaxf(v0, v1));
        }
        if (i < r1) {
            float v = fmaxf(bf2f(h[(size_t)i * 256 + c]) * sc + sh, 0.f);
            s += v;
            m = fmaxf(m, v);
        }
        float cnt = fmaxf((float)(r1 - r0), 1.f);
        z[(size_t)g * 640 + c] = s / cnt;
        z[(size_t)g * 640 + 256 + c] = m;
    } else {
        // ---- solvent MLP: relu(sfp @ Wsm + bsm) -> z[:,512:640], K=128 ----
        const int r = t >> 7, c = t & 127;
        const int row0 = (bid - G_) * 2;
        for (int i = t; i < 256; i += 256) {
            int rr = i >> 7, kk = i & 127;
            int gr = row0 + rr;
            As[rr][kk] = (gr < G_) ? sfp[(size_t)gr * 128 + kk] : 0.f;
        }
        __syncthreads();
        float acc0 = 0.f, acc1 = 0.f;
        for (int k = 0; k < 128; k += 8) {
            float4 a0 = *reinterpret_cast<const float4*>(&As[r][k]);
            float4 a1 = *reinterpret_cast<const float4*>(&As[r][k + 4]);
            acc0 += a0.x * Wsm[(size_t)(k + 0) * 128 + c];
            acc1 += a0.y * Wsm[(size_t)(k + 1) * 128 + c];
            acc0 += a0.z * Wsm[(size_t)(k + 2) * 128 + c];
            acc1 += a0.w * Wsm[(size_t)(k + 3) * 128 + c];
            acc0 += a1.x * Wsm[(size_t)(k + 4) * 128 + c];
            acc1 += a1.y * Wsm[(size_t)(k + 5) * 128 + c];
            acc0 += a1.z * Wsm[(size_t)(k + 6) * 128 + c];
            acc1 += a1.w * Wsm[(size_t)(k + 7) * 128 + c];
        }
        int row = row0 + r;
        if (row < G_) {
            float v = fmaxf(acc0 + acc1 + bsm[c], 0.f);
            z[(size_t)row * 640 + 512 + c] = v;
        }
    }
}

// ---- final head with fused BNf apply+relu ---------------------------------
__global__ void final_head_bn(const float* __restrict__ f1,
                              const float* __restrict__ scale, const float* __restrict__ shift,
                              const float* __restrict__ Wf2, const float* __restrict__ bf2,
                              float* __restrict__ out, int G_)
{
    int w = (int)(((long long)blockIdx.x * blockDim.x + threadIdx.x) >> 6);
    int lane = threadIdx.x & 63;
    if (w >= G_) return;
    float s = 0.f;
    #pragma unroll
    for (int q = 0; q < 2; ++q) {
        int c = lane + q * 64;
        float v = fmaxf(f1[(size_t)w * 128 + c] * scale[c] + shift[c], 0.f);
        s += v * Wf2[c];
    }
    #pragma unroll
    for (int off = 32; off; off >>= 1) s += __shfl_down(s, off);
    if (lane == 0) out[w] = 1.f / (1.f + __expf(-(s + bf2[0])));
}

__global__ void sentinel(float* __restrict__ out, int n, float v)
{
    int i = blockIdx.x * blockDim.x + threadIdx.x;
    if (i < n) out[i] = v;
}

// ---------------------------------------------------------------------------
extern "C" void kernel_launch(void* const* d_in, const int* in_sizes, int n_in,
                              void* d_out, int out_size, void* d_ws, size_t ws_size,
                              hipStream_t stream)
{
    const float* x    = (const float*)d_in[0];
    const int*   ei   = (const int*)d_in[1];
    const int*   batch= (const int*)d_in[2];
    const float* sfp  = (const float*)d_in[3];
    const float* W1   = (const float*)d_in[4];
    const float* a1s  = (const float*)d_in[5];
    const float* a1d  = (const float*)d_in[6];
    const float* bn1g = (const float*)d_in[8];
    const float* bn1b = (const float*)d_in[9];
    const float* W2   = (const float*)d_in[10];
    const float* a2s  = (const float*)d_in[11];
    const float* a2d  = (const float*)d_in[12];
    const float* bn2g = (const float*)d_in[14];
    const float* bn2b = (const float*)d_in[15];
    const float* Wg   = (const float*)d_in[16];
    const float* bn3g = (const float*)d_in[18];
    const float* bn3b = (const float*)d_in[19];
    const float* Wsm  = (const float*)d_in[20];
    const float* bsm  = (const float*)d_in[21];
    const float* Wf1  = (const float*)d_in[22];
    const float* bnfg = (const float*)d_in[24];
    const float* bnfb = (const float*)d_in[25];
    const float* Wf2  = (const float*)d_in[26];
    const float* bf2  = (const float*)d_in[27];
    float* outp = (float*)d_out;

    const int N    = in_sizes[0] / 64;
    const int E    = in_sizes[1] / 2;
    const int G_   = in_sizes[3] / 128;
    const int Etot = E + N;
    const int* esrc = ei;
    const int* edst = ei + E;
    const int YB = 256;
    const int NB = cdiv(N, 1024);
    const int NYT = cdiv(N, 128);                 // GEMM row tiles
    const int NYT8 = cdiv(NYT, 8) * 8;            // padded for swizzle

    // ---- workspace (fp32-element offsets) ----
    float* ws = (float*)d_ws;
    size_t off = 0;
    float* accA  = ws + off; off += (size_t)N * 256;
    float* h3acc = ws + off; off += (size_t)N * 256;
    unsigned short* g1b   = (unsigned short*)accA;   // [N,512] bf16 L1 GEMM out
    unsigned short* g3b   = (unsigned short*)accA;   // [N,256] bf16 GCN-gather out
    unsigned short* h2all = (unsigned short*)accA;   // [N,1024] bf16 (spans accA+h3acc!)
    unsigned short* R1 = (unsigned short*)(ws + off); off += (size_t)N * 256; // N*512 bf16
    unsigned short* o1n = R1;
    unsigned short* hb  = (unsigned short*)(ws + off); off += (size_t)N * 128; // N*256 bf16
    unsigned short* xb  = (unsigned short*)(ws + off); off += (size_t)N * 32;  // N*64 bf16
    float* alsd = ws + off; off += (size_t)N * 8;
    float* dinv = ws + off; off += N;
    float* bsc = ws + off; off += 1024;
    float* bsh = ws + off; off += 1024;
    // ps/pq: base region (overwrite-style bn_part_bf, YB*512) + 4 atomic
    // regions zeroed once up front: P0 (512), P1 (512), G (256), F (128).
    float* ps  = ws + off; off += (size_t)YB * 1920;
    float* pq  = ws + off; off += (size_t)YB * 1920;
    float* psP0 = ps + (size_t)YB * 512;
    float* psP1 = ps + (size_t)YB * 1024;
    float* psG  = ps + (size_t)YB * 1536;
    float* psF  = ps + (size_t)YB * 1792;
    float* pqP0 = pq + (size_t)YB * 512;
    float* pqP1 = pq + (size_t)YB * 1024;
    float* pqG  = pq + (size_t)YB * 1536;
    float* pqF  = pq + (size_t)YB * 1792;
    float* z   = ws + off; off += (size_t)G_ * 640;
    float* f1  = ws + off; off += (size_t)G_ * 128;
    int* rowptr = (int*)(ws + off); off += (size_t)(N + 1);
    int* colc   = (int*)(ws + off); off += (size_t)Etot;
    int* gptr   = (int*)(ws + off); off += (size_t)(G_ + 1);
    int* bsums  = (int*)(ws + off); off += 256;
    off = (off + 3) & ~(size_t)3;                 // 16B-align the bf16 tables
    unsigned short* vat1 = (unsigned short*)(ws + off); off += 128 * 64 / 2;
    unsigned short* vat2 = (unsigned short*)(ws + off); off += 128 * 512 / 2;
    unsigned short* W1bdt = (unsigned short*)(ws + off); off += 512 * 256 / 2;
    unsigned short* W2t = (unsigned short*)(ws + off); off += 512 * 1024 / 2;
    unsigned short* Wgt = (unsigned short*)(ws + off); off += 1024 * 256 / 2;
    int* cursor = (int*)alsd;   // alias: cursor dead before alsd is written
    size_t need = off * 4;
    if (ws_size < need) {
        sentinel<<<cdiv(out_size, 256), 256, 0, stream>>>(outp, out_size, (float)(ws_size >> 20));
        return;
    }

    const int BLK = 256;
    dim3 blk(BLK);

    // zero the atomic-stats regions ONCE, up front (overlaps prep/CSR work)
    hipMemsetAsync(psP0, 0, (size_t)YB * 1408 * 4, stream);  // P0+P1+G+F contiguous
    hipMemsetAsync(pqP0, 0, (size_t)YB * 1408 * 4, stream);

    // ============ MEGA-PREP (weights, x cast, vat, cursor, gptr) ============
    const int c0 = 512;
    const int c1 = c0 + 2048;
    const int c2 = c1 + 1024;
    const int c3 = c2 + cdiv((long long)N * 16, 256);
    const int c4 = c3 + 64;
    const int c5 = c4 + 512;
    const int c6 = c5 + cdiv(N, 256);
    const int c7 = c6 + cdiv(G_ + 1, 256);
    prep_all<<<c7, blk, 0, stream>>>(W1, W2, Wg, x, a1s, a1d, a2s, a2d, batch,
                                     W1bdt, W2t, Wgt, xb, vat1, vat2,
                                     cursor, gptr, N, G_,
                                     c0, c1, c2, c3, c4, c5, c6);

    // ================= build CSR (dst -> src) ===============================
    hist_dst<<<cdiv(E, BLK), blk, 0, stream>>>(edst, E, cursor);
    scan_blk<<<NB, blk, 0, stream>>>(cursor, rowptr, bsums, N);
    scan_tops<<<1, blk, 0, stream>>>(bsums, rowptr, NB, N);
    scan_add<<<cdiv(N, BLK), blk, 0, stream>>>(rowptr, cursor, bsums, N);
    { int NBsc = cdiv(Etot, BLK);
      csr_scatter_dinv<<<NBsc + cdiv(N, BLK), blk, 0, stream>>>(
          esrc, edst, E, Etot, cursor, colc, rowptr, dinv, N, NBsc); }

    // ====== GAT layer 1, AGGREGATE-FIRST: logits -> agg(x, exp inline) -> GEMM
    logits_valu<<<cdiv(N, 32), blk, 0, stream>>>(xb, vat1, alsd, N, 64);
    gat_agg4_64<<<cdiv((long long)N * 64, BLK), blk, 0, stream>>>(
        rowptr, colc, xb, alsd, hb, N);
    gemm_mfma<<<NYT8 * 4, blk, 0, stream>>>(hb, W1bdt, g1b, N, 256, 256, 256, 512, 4, NYT);
    { dim3 g(1, YB); bn_part_bf<512><<<g, blk, 0, stream>>>(g1b, 512, ps, pq, N, YB); }
    bn_reduce_fin<512><<<8, blk, 0, stream>>>(ps, pq, bn1g, bn1b, bsc, bsh, YB, 1.f / N);
    // fused: relu(bn(g1b)) -> o1n  AND layer-2 logits -> alsd (persistent blocks)
    bn_apply_logits512<<<2048, blk, 0, stream>>>(
        g1b, bsc, bsh, vat2, o1n, alsd, N, 2048);

    // ======= GAT layer 2: ONE batched GEMM (512 -> 1024), XCD-swizzled =====
    gemm_mfma<<<NYT8 * 8, blk, 0, stream>>>(o1n, W2t, h2all, N, 512, 512, 512, 1024, 8, NYT);
    // R1 (o1n) dead after the GEMM: head-pair gathers (exp + BN-stats fused)
    // -> R1; fin; apply back into h2all column block. Per-site stats regions.
    for (int pr = 0; pr < 2; ++pr) {
        float* pssite = pr ? psP1 : psP0;
        float* pqsite = pr ? pqP1 : pqP0;
        gat_gather512_ex<<<cdiv((long long)N * 64, BLK), blk, 0, stream>>>(
            rowptr, colc, h2all + pr * 512, 1024, alsd, pr, R1, pssite, pqsite, N);
        bn_reduce_fin<512><<<8, blk, 0, stream>>>(pssite, pqsite, bn2g + pr * 512, bn2b + pr * 512,
                                                  bsc + pr * 512, bsh + pr * 512, YB, 1.f / N);
        bn_apply_bfbf<<<cdiv((long long)N * 128, BLK), blk, 0, stream>>>(
            R1, bsc + pr * 512, bsh + pr * 512, h2all + pr * 512, N * 128, 128, 512, 1024);
    }

    // GCN GEMM: K=1024, 2 column blocks, XCD-swizzled (A read ~once)
    gemm_mfma<<<NYT8 * 2, blk, 0, stream>>>(h2all, Wgt, hb, N, 1024, 1024, 1024, 256, 2, NYT);

    // ================= GCN aggregation (BN3 stats fused) ====================
    gcn_gather256<<<cdiv((long long)N * 64, BLK), blk, 0, stream>>>(
        rowptr, colc, hb, dinv, g3b, psG, pqG, N);
    bn_reduce_fin<256><<<4, blk, 0, stream>>>(psG, pqG, bn3g, bn3b, bsc, bsh, YB, 1.f / N);

    // ======== Pooling (BN3+relu fused) + solvent MLP, ONE launch ============
    pool_solv<<<G_ + cdiv(G_, 2), blk, 0, stream>>>(
        g3b, bsc, bsh, gptr, z, G_, sfp, Wsm, bsm);

    // ================= Head (BNf stats fused into the GEMM epilogue) ========
    gemm_small<false><<<cdiv(G_, 2), blk, 0, stream>>>(
        z, Wf1, nullptr, f1, G_, 640, 640, 128, 128, psF, pqF);
    bn_reduce_fin<128><<<2, blk, 0, stream>>>(psF, pqF, bnfg, bnfb, bsc, bsh, YB, 1.f / G_);
    final_head_bn<<<cdiv((long long)G_ * 64, BLK), blk, 0, stream>>>(
        f1, bsc, bsh, Wf2, bf2, outp, G_);
}

// Round 15
// 699.773 us; speedup vs baseline: 1.0974x; 1.0831x over previous
//
#include <hip/hip_runtime.h>
#include <cmath>

#define LEAK 0.2f
#define BN_EPS 1e-5f

static inline int cdiv(long long a, long long b){ return (int)((a + b - 1) / b); }

typedef __attribute__((ext_vector_type(8))) short bf16x8;
typedef __attribute__((ext_vector_type(4))) float f32x4;

// ---- bf16 helpers (manual, RNE) -------------------------------------------
__device__ __forceinline__ float bf2f(unsigned short u){
    return __uint_as_float(((unsigned int)u) << 16);
}
__device__ __forceinline__ unsigned short f2bf(float f){
    unsigned int u = __float_as_uint(f);
    u += 0x7FFFu + ((u >> 16) & 1u);
    return (unsigned short)(u >> 16);
}
__device__ __forceinline__ float edge_ex(float s, float d){
    float t = s + d;
    t = (t >= 0.f) ? t : LEAK * t;
    return __expf(t);
}

// async global->LDS, 16B per lane. LDS dest must be linear: wave-uniform base
// + lane*16 (m104). Source address is per-lane -> swizzle goes on the SOURCE.
#define GLOAD_LDS16(gsrc, ldst) \
    __builtin_amdgcn_global_load_lds( \
        (const __attribute__((address_space(1))) unsigned int*)(gsrc), \
        (__attribute__((address_space(3))) unsigned int*)(ldst), 16, 0, 0)

// ---------------------------------------------------------------------------
// MFMA bf16 GEMM (128x128 tile, BK=64, 4 waves x 4x4 16x16x32 MFMAs).
// m97 staging + BK=64 + both-sides XOR chunk swizzle (R4: 82us, 0 conflicts).
// XCD-aware 1D swizzle. grid.x = 8 * cdiv(NYT,8) * NX.  K % 64 == 0.
// R13: LDS-repack epilogue for coalesced 16B stores (79.5 -> 77.2us).
// R15: optional fused BN stats -- register-only shfl column-reduce then
// direct atomicAdd from lanes<16 (no LDS, no extra barrier; R10's failure
// modes removed). Saves the separate bn_part_bf pass over the output.
// ---------------------------------------------------------------------------
__global__ __launch_bounds__(256) void gemm_mfma(
    const unsigned short* __restrict__ A, const unsigned short* __restrict__ Bt,
    unsigned short* __restrict__ D, int M, int K, int lda, int ldb, int ldc,
    int NX, int NYT, float* __restrict__ ps, float* __restrict__ pq, int Dbn)
{
    const int id = blockIdx.x;
    const int xcd = id & 7;
    const int j = id >> 3;
    const int bx = j % NX;
    const int by = (j / NX) * 8 + xcd;
    if (by >= NYT) return;

    __shared__ unsigned short As[128 * 64];
    __shared__ unsigned short Bs[128 * 64];
    const int t = threadIdx.x;
    const int row0 = by * 128, col0 = bx * 128;
    const int lane = t & 63, wv = t >> 6;
    const int wm = (wv >> 1) << 6, wn = (wv & 1) << 6;
    const int lm = lane & 15, lq = lane >> 4;

    const int sr  = t >> 3;                       // 0..31
    const int scs = (t & 7) << 3;                 // LDS col in shorts (linear)
    const int gsw = (((t & 7) ^ (sr & 7)) << 3);  // global col in shorts
    const unsigned short* ap[4];
    const unsigned short* bp[4];
    unsigned short* la[4];
    unsigned short* lb[4];
    #pragma unroll
    for (int q = 0; q < 4; ++q) {
        int r = sr + q * 32;
        int gra = row0 + r; if (gra >= M) gra = M - 1;
        ap[q] = A  + (size_t)gra * lda + gsw;
        bp[q] = Bt + (size_t)(col0 + r) * ldb + gsw;
        la[q] = &As[r * 64 + scs];
        lb[q] = &Bs[r * 64 + scs];
    }

    f32x4 acc[4][4] = {};
    const int rx = lm & 7;                        // row&7 for this lane's reads

    for (int k0 = 0; k0 < K; k0 += 64) {
        #pragma unroll
        for (int q = 0; q < 4; ++q) {
            GLOAD_LDS16(ap[q] + k0, la[q]);
            GLOAD_LDS16(bp[q] + k0, lb[q]);
        }
        __syncthreads();

        #pragma unroll
        for (int kk = 0; kk < 2; ++kk) {
            const int ck = (((kk << 2) + lq) ^ rx) << 3;   // swizzled chunk col
            bf16x8 af[4], bfr[4];
            #pragma unroll
            for (int mi = 0; mi < 4; ++mi)
                af[mi] = *(const bf16x8*)&As[(wm + mi * 16 + lm) * 64 + ck];
            #pragma unroll
            for (int ni = 0; ni < 4; ++ni)
                bfr[ni] = *(const bf16x8*)&Bs[(wn + ni * 16 + lm) * 64 + ck];
            #pragma unroll
            for (int mi = 0; mi < 4; ++mi)
                #pragma unroll
                for (int ni = 0; ni < 4; ++ni)
                    acc[mi][ni] = __builtin_amdgcn_mfma_f32_16x16x32_bf16(
                        af[mi], bfr[ni], acc[mi][ni], 0, 0, 0);
        }
        __syncthreads();
    }
    // K-loop's trailing barrier: all ds_reads drained -> As/Bs reusable.

    // ---- epilogue: repack C tile via LDS for coalesced 16B stores ----------
    #pragma unroll
    for (int mi = 0; mi < 4; ++mi) {
        #pragma unroll
        for (int r = 0; r < 4; ++r) {
            int row = wm + mi * 16 + lq * 4 + r;
            unsigned short* base = (row < 64) ? &As[row * 128] : &Bs[(row - 64) * 128];
            #pragma unroll
            for (int ni = 0; ni < 4; ++ni) {
                int col = (wn + ni * 16 + lm) ^ (lq << 4);
                base[col] = f2bf(acc[mi][ni][r]);
            }
        }
    }
    __syncthreads();
    #pragma unroll
    for (int i = 0; i < 8; ++i) {
        int idx = i * 256 + t;                 // 0..2047: 128 rows x 16 chunks
        int row = idx >> 4;
        int lqr = (row >> 2) & 3;
        int c8l = (idx & 15) << 3;             // logical chunk col
        int c8p = c8l ^ (lqr << 4);            // physical (swizzled) col
        int grow = row0 + row;
        if (grow < M) {
            const unsigned short* base = (row < 64) ? &As[row * 128] : &Bs[(row - 64) * 128];
            bf16x8 v = *(const bf16x8*)&base[c8p];
            *(bf16x8*)(D + (size_t)grow * ldc + col0 + c8l) = v;
        }
    }

    // ---- optional fused BN stats (register-only; no LDS, no extra barrier) -
    if (ps) {
        float cs[4] = {}, cq[4] = {};
        #pragma unroll
        for (int mi = 0; mi < 4; ++mi) {
            int row_b = row0 + wm + mi * 16 + lq * 4;
            #pragma unroll
            for (int ni = 0; ni < 4; ++ni)
                #pragma unroll
                for (int r = 0; r < 4; ++r)
                    if (row_b + r < M) {
                        float v = acc[mi][ni][r];
                        cs[ni] += v; cq[ni] += v * v;
                    }
        }
        // reduce across the 4 lq groups (lanes differing in bits 4,5):
        // after this, lanes 0..15 hold column sums over the wave's 64 rows.
        #pragma unroll
        for (int ni = 0; ni < 4; ++ni) {
            cs[ni] += __shfl_xor(cs[ni], 16); cs[ni] += __shfl_xor(cs[ni], 32);
            cq[ni] += __shfl_xor(cq[ni], 16); cq[ni] += __shfl_xor(cq[ni], 32);
        }
        if (lane < 16) {
            size_t slot = (size_t)(blockIdx.x & 255) * Dbn + col0;
            #pragma unroll
            for (int ni = 0; ni < 4; ++ni) {
                int c = wn + ni * 16 + lane;
                atomicAdd(&ps[slot + c], cs[ni]);
                atomicAdd(&pq[slot + c], cq[ni]);
            }
        }
    }
}

// ---------------------------------------------------------------------------
// Logits: C[M,8] = A[M,K] @ vat[8,K]^T (used for K=64, layer 1).
// ---------------------------------------------------------------------------
__global__ __launch_bounds__(256) void logits_valu(
    const unsigned short* __restrict__ A, const unsigned short* __restrict__ vat,
    float* __restrict__ C, int M, int K)
{
    __shared__ unsigned short vs[8 * 512];
    const int t = threadIdx.x;
    for (int i = t; i < K; i += 256)
        *(bf16x8*)&vs[i * 8] = *(const bf16x8*)(vat + (size_t)i * 8);
    __syncthreads();

    const int lane = t & 63;
    const int w = blockIdx.x * 4 + (t >> 6);
    const int Gl = K >> 3;                     // lanes per row (8 or 64)
    const int rpw = 64 / Gl;                   // rows per wave
    const int sub = lane / Gl;
    const int li = lane - sub * Gl;
    long long row = (long long)w * rpw + sub;
    if (row >= M) return;

    bf16x8 hv = *(const bf16x8*)(A + row * K + li * 8);
    float hf[8];
    #pragma unroll
    for (int j = 0; j < 8; ++j) hf[j] = bf2f((unsigned short)hv[j]);

    float s[8];
    #pragma unroll
    for (int o = 0; o < 8; ++o) {
        bf16x8 v = *(const bf16x8*)&vs[o * K + li * 8];
        float acc = 0.f;
        #pragma unroll
        for (int j = 0; j < 8; ++j) acc += hf[j] * bf2f((unsigned short)v[j]);
        s[o] = acc;
    }
    for (int off = Gl >> 1; off; off >>= 1) {
        #pragma unroll
        for (int o = 0; o < 8; ++o) s[o] += __shfl_xor(s[o], off);
    }
    #pragma unroll
    for (int o = 0; o < 8; ++o)
        if (li == o) C[row * 8 + o] = s[o];
}

// ---------------------------------------------------------------------------
// FUSED: relu(bn(g1b)) -> o1n bf16  AND  layer-2 logits (K=512).
// R14: PERSISTENT blocks -- vat2 staged ONCE per block, grid-stride row loop.
// ---------------------------------------------------------------------------
__global__ __launch_bounds__(256) void bn_apply_logits512(
    const unsigned short* __restrict__ g1b,
    const float* __restrict__ scale, const float* __restrict__ shift,
    const unsigned short* __restrict__ vat,
    unsigned short* __restrict__ o1n, float* __restrict__ C, int M, int nblk)
{
    __shared__ unsigned short vs[8 * 512];
    const int t = threadIdx.x;
    for (int i = t; i < 512; i += 256)
        *(bf16x8*)&vs[i * 8] = *(const bf16x8*)(vat + (size_t)i * 8);
    __syncthreads();

    const int lane = t & 63;
    const long long stride = (long long)nblk * 4;
    for (long long row = (long long)blockIdx.x * 4 + (t >> 6); row < M; row += stride) {
        bf16x8 u = *(const bf16x8*)(g1b + row * 512 + lane * 8);
        float4 sc0 = *(const float4*)(scale + lane * 8);
        float4 sc1 = *(const float4*)(scale + lane * 8 + 4);
        float4 sh0 = *(const float4*)(shift + lane * 8);
        float4 sh1 = *(const float4*)(shift + lane * 8 + 4);
        float hf[8];
        hf[0] = fmaxf(bf2f((unsigned short)u[0]) * sc0.x + sh0.x, 0.f);
        hf[1] = fmaxf(bf2f((unsigned short)u[1]) * sc0.y + sh0.y, 0.f);
        hf[2] = fmaxf(bf2f((unsigned short)u[2]) * sc0.z + sh0.z, 0.f);
        hf[3] = fmaxf(bf2f((unsigned short)u[3]) * sc0.w + sh0.w, 0.f);
        hf[4] = fmaxf(bf2f((unsigned short)u[4]) * sc1.x + sh1.x, 0.f);
        hf[5] = fmaxf(bf2f((unsigned short)u[5]) * sc1.y + sh1.y, 0.f);
        hf[6] = fmaxf(bf2f((unsigned short)u[6]) * sc1.z + sh1.z, 0.f);
        hf[7] = fmaxf(bf2f((unsigned short)u[7]) * sc1.w + sh1.w, 0.f);
        bf16x8 o;
        #pragma unroll
        for (int j = 0; j < 8; ++j) o[j] = (short)f2bf(hf[j]);
        *(bf16x8*)(o1n + row * 512 + lane * 8) = o;

        float s[8];
        #pragma unroll
        for (int oo = 0; oo < 8; ++oo) {
            bf16x8 v = *(const bf16x8*)&vs[oo * 512 + lane * 8];
            float acc = 0.f;
            #pragma unroll
            for (int j = 0; j < 8; ++j) acc += hf[j] * bf2f((unsigned short)v[j]);
            s[oo] = acc;
        }
        #pragma unroll
        for (int off = 32; off; off >>= 1) {
            #pragma unroll
            for (int oo = 0; oo < 8; ++oo) s[oo] += __shfl_xor(s[oo], off);
        }
        #pragma unroll
        for (int oo = 0; oo < 8; ++oo)
            if (lane == oo) C[row * 8 + oo] = s[oo];
    }
}

// ---------------------------------------------------------------------------
// MEGA-PREP: all weight conversions + x cast + vat + cursor init + group LB
// in ONE launch, segmented by blockIdx ranges (each branch is block-uniform).
// ---------------------------------------------------------------------------
__global__ __launch_bounds__(256) void prep_all(
    const float* __restrict__ W1, const float* __restrict__ W2,
    const float* __restrict__ Wg, const float* __restrict__ x,
    const float* __restrict__ a1s, const float* __restrict__ a1d,
    const float* __restrict__ a2s, const float* __restrict__ a2d,
    const int* __restrict__ batch,
    unsigned short* __restrict__ W1bdt, unsigned short* __restrict__ W2t,
    unsigned short* __restrict__ Wgt, unsigned short* __restrict__ xb,
    unsigned short* __restrict__ vat1, unsigned short* __restrict__ vat2,
    int* __restrict__ cursor, int* __restrict__ gptr,
    int N, int G_,
    int c0, int c1, int c2, int c3, int c4, int c5, int c6)
{
    const int t = threadIdx.x;
    const int bid = blockIdx.x;
    if (bid < c0) {
        int i = bid * 256 + t;                 // exactly 512*256
        int o = i >> 8, k = i & 255;
        unsigned short v = 0;
        if ((k >> 6) == (o >> 7)) v = f2bf(W1[(size_t)(k & 63) * 512 + o]);
        W1bdt[i] = v;
    } else if (bid < c1) {
        int i = (bid - c0) * 256 + t;          // exactly 512*1024
        int k = i >> 10, n = i & 1023;
        W2t[(size_t)n * 512 + k] = f2bf(W2[i]);
    } else if (bid < c2) {
        int i = (bid - c1) * 256 + t;          // exactly 1024*256
        int k = i >> 8, n = i & 255;
        Wgt[(size_t)n * 1024 + k] = f2bf(Wg[i]);
    } else if (bid < c3) {
        int i = (bid - c2) * 256 + t;
        if (i < N * 16) {
            float4 v = *reinterpret_cast<const float4*>(x + (size_t)i * 4);
            ushort4 o = { f2bf(v.x), f2bf(v.y), f2bf(v.z), f2bf(v.w) };
            *reinterpret_cast<ushort4*>(xb + (size_t)i * 4) = o;
        }
    } else if (bid < c4) {
        int w = (((bid - c3) * 256 + t) >> 6);
        int lane = t & 63;
        int k = w >> 2, h = w & 3;
        const float* wp = W1 + (size_t)k * 512 + h * 128;
        const float* as = a1s + h * 128;
        const float* ad = a1d + h * 128;
        float s = 0.f, d = 0.f;
        for (int c = lane; c < 128; c += 64) {
            float v = wp[c];
            s += v * as[c];
            d += v * ad[c];
        }
        #pragma unroll
        for (int off = 32; off; off >>= 1) {
            s += __shfl_down(s, off);
            d += __shfl_down(d, off);
        }
        if (lane == 0) {
            vat1[(size_t)h * 64 + k] = f2bf(s);
            vat1[(size_t)(4 + h) * 64 + k] = f2bf(d);
        }
    } else if (bid < c5) {
        int w = (((bid - c4) * 256 + t) >> 6);
        int lane = t & 63;
        int k = w >> 2, h = w & 3;
        const float* wp = W2 + (size_t)k * 1024 + h * 256;
        const float* as = a2s + h * 256;
        const float* ad = a2d + h * 256;
        float s = 0.f, d = 0.f;
        for (int c = lane; c < 256; c += 64) {
            float v = wp[c];
            s += v * as[c];
            d += v * ad[c];
        }
        #pragma unroll
        for (int off = 32; off; off >>= 1) {
            s += __shfl_down(s, off);
            d += __shfl_down(d, off);
        }
        if (lane == 0) {
            vat2[(size_t)h * 512 + k] = f2bf(s);
            vat2[(size_t)(4 + h) * 512 + k] = f2bf(d);
        }
    } else if (bid < c6) {
        int i = (bid - c5) * 256 + t;
        if (i < N) cursor[i] = 1;
    } else {
        int g = (bid - c6) * 256 + t;
        if (g > G_) return;
        if (g == G_) { gptr[G_] = N; return; }
        int lo = 0, hi = N;
        while (lo < hi) { int mid = (lo + hi) >> 1; if (batch[mid] < g) lo = mid + 1; else hi = mid; }
        gptr[g] = lo;
    }
}

// ---------------------------------------------------------------------------
// Small-M fp32 GEMM, Nc = 128: one output/thread, 2 rows/block, A in LDS.
// Optional fused BN stats (per-thread atomicAdd; cheap -- no extra sync).
// ---------------------------------------------------------------------------
template<bool RELU>
__global__ __launch_bounds__(256) void gemm_small(
    const float* __restrict__ A, const float* __restrict__ B,
    const float* __restrict__ bias, float* __restrict__ C,
    int M, int K, int lda, int ldb, int ldc,
    float* __restrict__ ps, float* __restrict__ pq)
{
    __shared__ float As[2][640];
    const int t = threadIdx.x;
    const int r = t >> 7, c = t & 127;
    const int row0 = blockIdx.x * 2;
    for (int i = t; i < 2 * K; i += 256) {
        int rr = i / K, kk = i - rr * K;
        int gr = row0 + rr;
        As[rr][kk] = (gr < M) ? A[(size_t)gr * lda + kk] : 0.f;
    }
    __syncthreads();
    float acc0 = 0.f, acc1 = 0.f;
    for (int k = 0; k < K; k += 8) {
        float4 a0 = *reinterpret_cast<const float4*>(&As[r][k]);
        float4 a1 = *reinterpret_cast<const float4*>(&As[r][k + 4]);
        acc0 += a0.x * B[(size_t)(k + 0) * ldb + c];
        acc1 += a0.y * B[(size_t)(k + 1) * ldb + c];
        acc0 += a0.z * B[(size_t)(k + 2) * ldb + c];
        acc1 += a0.w * B[(size_t)(k + 3) * ldb + c];
        acc0 += a1.x * B[(size_t)(k + 4) * ldb + c];
        acc1 += a1.y * B[(size_t)(k + 5) * ldb + c];
        acc0 += a1.z * B[(size_t)(k + 6) * ldb + c];
        acc1 += a1.w * B[(size_t)(k + 7) * ldb + c];
    }
    int row = row0 + r;
    if (row < M) {
        float v = acc0 + acc1;
        if (bias) v += bias[c];
        if (RELU) v = fmaxf(v, 0.f);
        C[(size_t)row * ldc + c] = v;
        if (ps) {
            size_t slot = (size_t)(blockIdx.x & 255) * 128 + c;
            atomicAdd(&ps[slot], v);
            atomicAdd(&pq[slot], v * v);
        }
    }
}

// ============================ CSR build ====================================
__device__ __forceinline__ int e_src(const int* es, int E, int k){ return k < E ? es[k] : k - E; }
__device__ __forceinline__ int e_dst(const int* ed, int E, int k){ return k < E ? ed[k] : k - E; }

__global__ void hist_dst(const int* __restrict__ ed, int E, int* __restrict__ cnt)
{
    int k = blockIdx.x * blockDim.x + threadIdx.x;
    if (k < E) atomicAdd(&cnt[ed[k]], 1);
}

__global__ __launch_bounds__(256) void scan_blk(const int* __restrict__ cnt,
                                                int* __restrict__ rowptr,
                                                int* __restrict__ bsums, int n)
{
    __shared__ int ts[256];
    const int t = threadIdx.x;
    const int i0 = blockIdx.x * 1024 + t * 4;
    int4 v = {0, 0, 0, 0};
    if (i0 + 3 < n) v = *reinterpret_cast<const int4*>(cnt + i0);
    else {
        if (i0 + 0 < n) v.x = cnt[i0 + 0];
        if (i0 + 1 < n) v.y = cnt[i0 + 1];
        if (i0 + 2 < n) v.z = cnt[i0 + 2];
        if (i0 + 3 < n) v.w = cnt[i0 + 3];
    }
    int lsum = v.x + v.y + v.z + v.w;
    ts[t] = lsum;
    __syncthreads();
    #pragma unroll
    for (int off = 1; off < 256; off <<= 1) {
        int u = (t >= off) ? ts[t - off] : 0;
        __syncthreads();
        ts[t] += u;
        __syncthreads();
    }
    int excl = ts[t] - lsum;
    if (i0 + 0 < n) rowptr[i0 + 0] = excl;
    if (i0 + 1 < n) rowptr[i0 + 1] = excl + v.x;
    if (i0 + 2 < n) rowptr[i0 + 2] = excl + v.x + v.y;
    if (i0 + 3 < n) rowptr[i0 + 3] = excl + v.x + v.y + v.z;
    if (t == 255) bsums[blockIdx.x] = ts[255];
}

__global__ __launch_bounds__(256) void scan_tops(int* __restrict__ bsums,
                                                 int* __restrict__ rowptr, int nb, int n)
{
    __shared__ int ts[256];
    const int t = threadIdx.x;
    int v = (t < nb) ? bsums[t] : 0;
    ts[t] = v;
    __syncthreads();
    #pragma unroll
    for (int off = 1; off < 256; off <<= 1) {
        int u = (t >= off) ? ts[t - off] : 0;
        __syncthreads();
        ts[t] += u;
        __syncthreads();
    }
    if (t < nb) bsums[t] = ts[t] - v;
    if (t == 255) rowptr[n] = ts[255];
}

__global__ void scan_add(int* __restrict__ rowptr, int* __restrict__ cursor,
                         const int* __restrict__ bsums, int n)
{
    int i = blockIdx.x * blockDim.x + threadIdx.x;
    if (i >= n) return;
    int r = rowptr[i] + bsums[i >> 10];
    rowptr[i] = r;
    cursor[i] = r;
}

// scatter (no dstarr) + dinv, one launch (blockIdx split)
__global__ void csr_scatter_dinv(const int* __restrict__ es, const int* __restrict__ ed,
                                 int E, int Etot, int* __restrict__ cursor,
                                 int* __restrict__ col,
                                 const int* __restrict__ rowptr,
                                 float* __restrict__ dinv, int N, int NBsc)
{
    const int bid = blockIdx.x;
    const int t = threadIdx.x;
    if (bid < NBsc) {
        int k = bid * 256 + t;
        if (k >= Etot) return;
        int sn = e_src(es, E, k), dn = e_dst(ed, E, k);
        int pos = atomicAdd(&cursor[dn], 1);
        col[pos] = sn;
    } else {
        int i = (bid - NBsc) * 256 + t;
        if (i < N) dinv[i] = rsqrtf(fmaxf((float)(rowptr[i + 1] - rowptr[i]), 1.f));
    }
}

// ====== layer-1 AGGREGATE-FIRST gather, exp fused, 2-edge ILP unroll =======
__global__ void gat_agg4_64(const int* __restrict__ rowptr, const int* __restrict__ col,
                            const unsigned short* __restrict__ xb,
                            const float* __restrict__ alsd,
                            unsigned short* __restrict__ agg, int N)
{
    int w = (int)(((long long)blockIdx.x * blockDim.x + threadIdx.x) >> 6);
    int lane = threadIdx.x & 63;
    if (w >= N) return;
    float4 dt = *reinterpret_cast<const float4*>(alsd + (size_t)w * 8 + 4);
    int r0 = rowptr[w], r1 = rowptr[w + 1];
    float a0 = 0.f, a1 = 0.f, a2 = 0.f, a3 = 0.f;
    float s0 = 0.f, s1 = 0.f, s2 = 0.f, s3 = 0.f;
    int e = r0;
    for (; e + 1 < r1; e += 2) {
        int snA = col[e], snB = col[e + 1];
        float4 stA = *reinterpret_cast<const float4*>(alsd + (size_t)snA * 8);
        float4 stB = *reinterpret_cast<const float4*>(alsd + (size_t)snB * 8);
        float xA = bf2f(xb[(size_t)snA * 64 + lane]);
        float xB = bf2f(xb[(size_t)snB * 64 + lane]);
        float eA0 = edge_ex(stA.x, dt.x), eB0 = edge_ex(stB.x, dt.x);
        float eA1 = edge_ex(stA.y, dt.y), eB1 = edge_ex(stB.y, dt.y);
        float eA2 = edge_ex(stA.z, dt.z), eB2 = edge_ex(stB.z, dt.z);
        float eA3 = edge_ex(stA.w, dt.w), eB3 = edge_ex(stB.w, dt.w);
        a0 += eA0 * xA + eB0 * xB;  s0 += eA0 + eB0;
        a1 += eA1 * xA + eB1 * xB;  s1 += eA1 + eB1;
        a2 += eA2 * xA + eB2 * xB;  s2 += eA2 + eB2;
        a3 += eA3 * xA + eB3 * xB;  s3 += eA3 + eB3;
    }
    if (e < r1) {
        int sn = col[e];
        float4 st = *reinterpret_cast<const float4*>(alsd + (size_t)sn * 8);
        float xA = bf2f(xb[(size_t)sn * 64 + lane]);
        float e0 = edge_ex(st.x, dt.x);
        float e1 = edge_ex(st.y, dt.y);
        float e2 = edge_ex(st.z, dt.z);
        float e3 = edge_ex(st.w, dt.w);
        a0 += e0 * xA; s0 += e0;
        a1 += e1 * xA; s1 += e1;
        a2 += e2 * xA; s2 += e2;
        a3 += e3 * xA; s3 += e3;
    }
    unsigned short* op = agg + (size_t)w * 256 + lane;
    op[0]   = f2bf(a0 / fmaxf(s0, 1e-16f));
    op[64]  = f2bf(a1 / fmaxf(s1, 1e-16f));
    op[128] = f2bf(a2 / fmaxf(s2, 1e-16f));
    op[192] = f2bf(a3 / fmaxf(s3, 1e-16f));
}

// ====== layer-2 gather, TWO heads per pass, exp fused, FUSED BN STATS,
// ====== 2-edge ILP unroll. ps/pq per-site regions, zeroed once up front. ===
__global__ __launch_bounds__(256) void gat_gather512_ex(
    const int* __restrict__ rowptr, const int* __restrict__ col,
    const unsigned short* __restrict__ h, int ldh,
    const float* __restrict__ alsd, int pr,
    unsigned short* __restrict__ out,
    float* __restrict__ ps, float* __restrict__ pq, int N)
{
    const int t = threadIdx.x;
    const int lane = t & 63;
    const int wv = t >> 6;
    int w = (int)(((long long)blockIdx.x * 256 + t) >> 6);
    const bool valid = (w < N);

    float v0=0.f,v1=0.f,v2=0.f,v3=0.f;      // head slot 0 normalized values
    float u0=0.f,u1=0.f,u2=0.f,u3=0.f;      // head slot 1
    if (valid) {
        float2 dt = *reinterpret_cast<const float2*>(alsd + (size_t)w * 8 + 4 + 2 * pr);
        int r0 = rowptr[w], r1 = rowptr[w + 1];
        float s0 = 0.f, s1 = 0.f;
        float a00=0.f,a01=0.f,a02=0.f,a03=0.f;
        float a10=0.f,a11=0.f,a12=0.f,a13=0.f;
        int e = r0;
        for (; e + 1 < r1; e += 2) {
            int snA = col[e], snB = col[e + 1];
            float2 stA = *reinterpret_cast<const float2*>(alsd + (size_t)snA * 8 + 2 * pr);
            float2 stB = *reinterpret_cast<const float2*>(alsd + (size_t)snB * 8 + 2 * pr);
            const unsigned short* pA = h + (size_t)snA * ldh + lane * 4;
            const unsigned short* pB = h + (size_t)snB * ldh + lane * 4;
            ushort4 hA0 = *reinterpret_cast<const ushort4*>(pA);
            ushort4 hA1 = *reinterpret_cast<const ushort4*>(pA + 256);
            ushort4 hB0 = *reinterpret_cast<const ushort4*>(pB);
            ushort4 hB1 = *reinterpret_cast<const ushort4*>(pB + 256);
            float eA0 = edge_ex(stA.x, dt.x), eB0 = edge_ex(stB.x, dt.x);
            float eA1 = edge_ex(stA.y, dt.y), eB1 = edge_ex(stB.y, dt.y);
            s0 += eA0 + eB0; s1 += eA1 + eB1;
            a00 += bf2f(hA0.x) * eA0 + bf2f(hB0.x) * eB0;
            a01 += bf2f(hA0.y) * eA0 + bf2f(hB0.y) * eB0;
            a02 += bf2f(hA0.z) * eA0 + bf2f(hB0.z) * eB0;
            a03 += bf2f(hA0.w) * eA0 + bf2f(hB0.w) * eB0;
            a10 += bf2f(hA1.x) * eA1 + bf2f(hB1.x) * eB1;
            a11 += bf2f(hA1.y) * eA1 + bf2f(hB1.y) * eB1;
            a12 += bf2f(hA1.z) * eA1 + bf2f(hB1.z) * eB1;
            a13 += bf2f(hA1.w) * eA1 + bf2f(hB1.w) * eB1;
        }
        if (e < r1) {
            int sn = col[e];
            float2 st = *reinterpret_cast<const float2*>(alsd + (size_t)sn * 8 + 2 * pr);
            float e0 = edge_ex(st.x, dt.x);
            float e1 = edge_ex(st.y, dt.y);
            const unsigned short* p = h + (size_t)sn * ldh + lane * 4;
            ushort4 h0 = *reinterpret_cast<const ushort4*>(p);
            ushort4 h1 = *reinterpret_cast<const ushort4*>(p + 256);
            s0 += e0; s1 += e1;
            a00 += bf2f(h0.x) * e0; a01 += bf2f(h0.y) * e0;
            a02 += bf2f(h0.z) * e0; a03 += bf2f(h0.w) * e0;
            a10 += bf2f(h1.x) * e1; a11 += bf2f(h1.y) * e1;
            a12 += bf2f(h1.z) * e1; a13 += bf2f(h1.w) * e1;
        }
        float i0 = 1.f / fmaxf(s0, 1e-16f);
        float i1 = 1.f / fmaxf(s1, 1e-16f);
        v0 = a00*i0; v1 = a01*i0; v2 = a02*i0; v3 = a03*i0;
        u0 = a10*i1; u1 = a11*i1; u2 = a12*i1; u3 = a13*i1;
        ushort4 o0 = { f2bf(v0), f2bf(v1), f2bf(v2), f2bf(v3) };
        ushort4 o1 = { f2bf(u0), f2bf(u1), f2bf(u2), f2bf(u3) };
        unsigned short* op = out + (size_t)w * 512 + lane * 4;
        *reinterpret_cast<ushort4*>(op)       = o0;
        *reinterpret_cast<ushort4*>(op + 256) = o1;
    }

    __shared__ float ls[4][512];
    __shared__ float lq[4][512];
    int c0 = lane * 4;
    ls[wv][c0+0]=v0; ls[wv][c0+1]=v1; ls[wv][c0+2]=v2; ls[wv][c0+3]=v3;
    ls[wv][256+c0+0]=u0; ls[wv][256+c0+1]=u1; ls[wv][256+c0+2]=u2; ls[wv][256+c0+3]=u3;
    lq[wv][c0+0]=v0*v0; lq[wv][c0+1]=v1*v1; lq[wv][c0+2]=v2*v2; lq[wv][c0+3]=v3*v3;
    lq[wv][256+c0+0]=u0*u0; lq[wv][256+c0+1]=u1*u1; lq[wv][256+c0+2]=u2*u2; lq[wv][256+c0+3]=u3*u3;
    __syncthreads();
    const size_t slot = (size_t)(blockIdx.x & 255) * 512;
    #pragma unroll
    for (int c = t; c < 512; c += 256) {
        float s = ls[0][c] + ls[1][c] + ls[2][c] + ls[3][c];
        float q = lq[0][c] + lq[1][c] + lq[2][c] + lq[3][c];
        atomicAdd(&ps[slot + c], s);
        atomicAdd(&pq[slot + c], q);
    }
}

// ====== GCN gather (C=256), FUSED BN STATS =================================
__global__ __launch_bounds__(256) void gcn_gather256(
    const int* __restrict__ rowptr, const int* __restrict__ col,
    const unsigned short* __restrict__ h,
    const float* __restrict__ dinv,
    unsigned short* __restrict__ out,
    float* __restrict__ ps, float* __restrict__ pq, int N)
{
    const int t = threadIdx.x;
    const int lane = t & 63;
    const int wv = t >> 6;
    int w = (int)(((long long)blockIdx.x * 256 + t) >> 6);
    const bool valid = (w < N);

    float v0=0.f,v1=0.f,v2=0.f,v3=0.f;
    if (valid) {
        int r0 = rowptr[w], r1 = rowptr[w + 1];
        float a0 = 0.f, a1 = 0.f, a2 = 0.f, a3 = 0.f;
        int e = r0;
        for (; e + 1 < r1; e += 2) {
            int sn0 = col[e], sn1 = col[e + 1];
            float w0 = dinv[sn0], w1 = dinv[sn1];
            ushort4 hv0 = *reinterpret_cast<const ushort4*>(h + (size_t)sn0 * 256 + lane * 4);
            ushort4 hv1 = *reinterpret_cast<const ushort4*>(h + (size_t)sn1 * 256 + lane * 4);
            a0 += bf2f(hv0.x) * w0 + bf2f(hv1.x) * w1;
            a1 += bf2f(hv0.y) * w0 + bf2f(hv1.y) * w1;
            a2 += bf2f(hv0.z) * w0 + bf2f(hv1.z) * w1;
            a3 += bf2f(hv0.w) * w0 + bf2f(hv1.w) * w1;
        }
        if (e < r1) {
            int sn = col[e];
            float wv2 = dinv[sn];
            ushort4 hv = *reinterpret_cast<const ushort4*>(h + (size_t)sn * 256 + lane * 4);
            a0 += bf2f(hv.x) * wv2; a1 += bf2f(hv.y) * wv2;
            a2 += bf2f(hv.z) * wv2; a3 += bf2f(hv.w) * wv2;
        }
        float dn = dinv[w];
        v0 = a0 * dn; v1 = a1 * dn; v2 = a2 * dn; v3 = a3 * dn;
        ushort4 o = { f2bf(v0), f2bf(v1), f2bf(v2), f2bf(v3) };
        *reinterpret_cast<ushort4*>(out + (size_t)w * 256 + lane * 4) = o;
    }

    __shared__ float ls[4][256];
    __shared__ float lq[4][256];
    int c0 = lane * 4;
    ls[wv][c0+0]=v0; ls[wv][c0+1]=v1; ls[wv][c0+2]=v2; ls[wv][c0+3]=v3;
    lq[wv][c0+0]=v0*v0; lq[wv][c0+1]=v1*v1; lq[wv][c0+2]=v2*v2; lq[wv][c0+3]=v3*v3;
    __syncthreads();
    const size_t slot = (size_t)(blockIdx.x & 255) * 256;
    if (t < 256) {
        int c = t;
        float s = ls[0][c] + ls[1][c] + ls[2][c] + ls[3][c];
        float q = lq[0][c] + lq[1][c] + lq[2][c] + lq[3][c];
        atomicAdd(&ps[slot + c], s);
        atomicAdd(&pq[slot + c], q);
    }
}

// ---- BN finalize: PARALLEL over column groups (grid.x = D/64) -------------
template<int D>
__global__ __launch_bounds__(256) void bn_reduce_fin(
    const float* __restrict__ ps, const float* __restrict__ pq,
    const float* __restrict__ g, const float* __restrict__ b,
    float* __restrict__ scale, float* __restrict__ shift, int Y, float invM)
{
    const int t = threadIdx.x;
    const int cl = t & 63;
    const int c = blockIdx.x * 64 + cl;
    const int ph = t >> 6;                 // 0..3
    float s = 0.f, q = 0.f;
    for (int y = ph; y < Y; y += 4) {
        s += ps[(size_t)y * D + c];
        q += pq[(size_t)y * D + c];
    }
    __shared__ float ls[4][64];
    __shared__ float lq[4][64];
    ls[ph][cl] = s; lq[ph][cl] = q;
    __syncthreads();
    if (ph == 0) {
        s = ls[0][cl] + ls[1][cl] + ls[2][cl] + ls[3][cl];
        q = lq[0][cl] + lq[1][cl] + lq[2][cl] + lq[3][cl];
        float mu = s * invM;
        float var = q * invM - mu * mu;
        float rs = rsqrtf(var + BN_EPS) * g[c];
        scale[c] = rs;
        shift[c] = b[c] - mu * rs;
    }
}

// relu(bn(x)): bf16 in (row stride ldx) -> bf16 out (row stride ldd)
__global__ void bn_apply_bfbf(const unsigned short* __restrict__ x,
                              const float* __restrict__ scale, const float* __restrict__ shift,
                              unsigned short* __restrict__ dst, int total4, int Cb4,
                              int ldx, int ldd)
{
    int i = blockIdx.x * blockDim.x + threadIdx.x;
    if (i >= total4) return;
    int r = i / Cb4, c4 = (i - r * Cb4) * 4;
    ushort4 u = *reinterpret_cast<const ushort4*>(x + (size_t)r * ldx + c4);
    float4 sc = *reinterpret_cast<const float4*>(scale + c4);
    float4 sh = *reinterpret_cast<const float4*>(shift + c4);
    ushort4 o;
    o.x = f2bf(fmaxf(bf2f(u.x) * sc.x + sh.x, 0.f));
    o.y = f2bf(fmaxf(bf2f(u.y) * sc.y + sh.y, 0.f));
    o.z = f2bf(fmaxf(bf2f(u.z) * sc.z + sh.z, 0.f));
    o.w = f2bf(fmaxf(bf2f(u.w) * sc.w + sh.w, 0.f));
    *reinterpret_cast<ushort4*>(dst + (size_t)r * ldd + c4) = o;
}

// ---- Pooling (BN3+relu fused) AND solvent MLP, one launch (blockIdx split) -
__global__ __launch_bounds__(256) void pool_solv(
    const unsigned short* __restrict__ h,
    const float* __restrict__ scale, const float* __restrict__ shift,
    const int* __restrict__ gptr, float* __restrict__ z, int G_,
    const float* __restrict__ sfp, const float* __restrict__ Wsm,
    const float* __restrict__ bsm)
{
    __shared__ float As[2][640];
    const int t = threadIdx.x;
    const int bid = blockIdx.x;
    if (bid < G_) {
        // ---- pooling with fused BN3 apply+relu (2-row ILP) ----
        int g = bid;
        int c = t;
        int r0 = gptr[g], r1 = gptr[g + 1];
        float sc = scale[c], sh = shift[c];
        float s = 0.f, m = 0.f;
        int i = r0;
        for (; i + 1 < r1; i += 2) {
            float v0 = fmaxf(bf2f(h[(size_t)i * 256 + c]) * sc + sh, 0.f);
            float v1 = fmaxf(bf2f(h[(size_t)(i + 1) * 256 + c]) * sc + sh, 0.f);
            s += v0 + v1;
            m = fmaxf(m, fmaxf(v0, v1));
        }
        if (i < r1) {
            float v = fmaxf(bf2f(h[(size_t)i * 256 + c]) * sc + sh, 0.f);
            s += v;
            m = fmaxf(m, v);
        }
        float cnt = fmaxf((float)(r1 - r0), 1.f);
        z[(size_t)g * 640 + c] = s / cnt;
        z[(size_t)g * 640 + 256 + c] = m;
    } else {
        // ---- solvent MLP: relu(sfp @ Wsm + bsm) -> z[:,512:640], K=128 ----
        const int r = t >> 7, c = t & 127;
        const int row0 = (bid - G_) * 2;
        for (int i = t; i < 256; i += 256) {
            int rr = i >> 7, kk = i & 127;
            int gr = row0 + rr;
            As[rr][kk] = (gr < G_) ? sfp[(size_t)gr * 128 + kk] : 0.f;
        }
        __syncthreads();
        float acc0 = 0.f, acc1 = 0.f;
        for (int k = 0; k < 128; k += 8) {
            float4 a0 = *reinterpret_cast<const float4*>(&As[r][k]);
            float4 a1 = *reinterpret_cast<const float4*>(&As[r][k + 4]);
            acc0 += a0.x * Wsm[(size_t)(k + 0) * 128 + c];
            acc1 += a0.y * Wsm[(size_t)(k + 1) * 128 + c];
            acc0 += a0.z * Wsm[(size_t)(k + 2) * 128 + c];
            acc1 += a0.w * Wsm[(size_t)(k + 3) * 128 + c];
            acc0 += a1.x * Wsm[(size_t)(k + 4) * 128 + c];
            acc1 += a1.y * Wsm[(size_t)(k + 5) * 128 + c];
            acc0 += a1.z * Wsm[(size_t)(k + 6) * 128 + c];
            acc1 += a1.w * Wsm[(size_t)(k + 7) * 128 + c];
        }
        int row = row0 + r;
        if (row < G_) {
            float v = fmaxf(acc0 + acc1 + bsm[c], 0.f);
            z[(size_t)row * 640 + 512 + c] = v;
        }
    }
}

// ---- final head with fused BNf apply+relu ---------------------------------
__global__ void final_head_bn(const float* __restrict__ f1,
                              const float* __restrict__ scale, const float* __restrict__ shift,
                              const float* __restrict__ Wf2, const float* __restrict__ bf2,
                              float* __restrict__ out, int G_)
{
    int w = (int)(((long long)blockIdx.x * blockDim.x + threadIdx.x) >> 6);
    int lane = threadIdx.x & 63;
    if (w >= G_) return;
    float s = 0.f;
    #pragma unroll
    for (int q = 0; q < 2; ++q) {
        int c = lane + q * 64;
        float v = fmaxf(f1[(size_t)w * 128 + c] * scale[c] + shift[c], 0.f);
        s += v * Wf2[c];
    }
    #pragma unroll
    for (int off = 32; off; off >>= 1) s += __shfl_down(s, off);
    if (lane == 0) out[w] = 1.f / (1.f + __expf(-(s + bf2[0])));
}

__global__ void sentinel(float* __restrict__ out, int n, float v)
{
    int i = blockIdx.x * blockDim.x + threadIdx.x;
    if (i < n) out[i] = v;
}

// ---------------------------------------------------------------------------
extern "C" void kernel_launch(void* const* d_in, const int* in_sizes, int n_in,
                              void* d_out, int out_size, void* d_ws, size_t ws_size,
                              hipStream_t stream)
{
    const float* x    = (const float*)d_in[0];
    const int*   ei   = (const int*)d_in[1];
    const int*   batch= (const int*)d_in[2];
    const float* sfp  = (const float*)d_in[3];
    const float* W1   = (const float*)d_in[4];
    const float* a1s  = (const float*)d_in[5];
    const float* a1d  = (const float*)d_in[6];
    const float* bn1g = (const float*)d_in[8];
    const float* bn1b = (const float*)d_in[9];
    const float* W2   = (const float*)d_in[10];
    const float* a2s  = (const float*)d_in[11];
    const float* a2d  = (const float*)d_in[12];
    const float* bn2g = (const float*)d_in[14];
    const float* bn2b = (const float*)d_in[15];
    const float* Wg   = (const float*)d_in[16];
    const float* bn3g = (const float*)d_in[18];
    const float* bn3b = (const float*)d_in[19];
    const float* Wsm  = (const float*)d_in[20];
    const float* bsm  = (const float*)d_in[21];
    const float* Wf1  = (const float*)d_in[22];
    const float* bnfg = (const float*)d_in[24];
    const float* bnfb = (const float*)d_in[25];
    const float* Wf2  = (const float*)d_in[26];
    const float* bf2  = (const float*)d_in[27];
    float* outp = (float*)d_out;

    const int N    = in_sizes[0] / 64;
    const int E    = in_sizes[1] / 2;
    const int G_   = in_sizes[3] / 128;
    const int Etot = E + N;
    const int* esrc = ei;
    const int* edst = ei + E;
    const int YB = 256;
    const int NB = cdiv(N, 1024);
    const int NYT = cdiv(N, 128);                 // GEMM row tiles
    const int NYT8 = cdiv(NYT, 8) * 8;            // padded for swizzle

    // ---- workspace (fp32-element offsets) ----
    float* ws = (float*)d_ws;
    size_t off = 0;
    float* accA  = ws + off; off += (size_t)N * 256;
    float* h3acc = ws + off; off += (size_t)N * 256;
    unsigned short* g1b   = (unsigned short*)accA;   // [N,512] bf16 L1 GEMM out
    unsigned short* g3b   = (unsigned short*)accA;   // [N,256] bf16 GCN-gather out
    unsigned short* h2all = (unsigned short*)accA;   // [N,1024] bf16 (spans accA+h3acc!)
    unsigned short* R1 = (unsigned short*)(ws + off); off += (size_t)N * 256; // N*512 bf16
    unsigned short* o1n = R1;
    unsigned short* hb  = (unsigned short*)(ws + off); off += (size_t)N * 128; // N*256 bf16
    unsigned short* xb  = (unsigned short*)(ws + off); off += (size_t)N * 32;  // N*64 bf16
    float* alsd = ws + off; off += (size_t)N * 8;
    float* dinv = ws + off; off += N;
    float* bsc = ws + off; off += 1024;
    float* bsh = ws + off; off += 1024;
    // ps/pq atomic regions, all zeroed once up front:
    // L1 (512, base), P0 (512), P1 (512), G (256), F (128).
    float* ps  = ws + off; off += (size_t)YB * 1920;
    float* pq  = ws + off; off += (size_t)YB * 1920;
    float* psP0 = ps + (size_t)YB * 512;
    float* psP1 = ps + (size_t)YB * 1024;
    float* psG  = ps + (size_t)YB * 1536;
    float* psF  = ps + (size_t)YB * 1792;
    float* pqP0 = pq + (size_t)YB * 512;
    float* pqP1 = pq + (size_t)YB * 1024;
    float* pqG  = pq + (size_t)YB * 1536;
    float* pqF  = pq + (size_t)YB * 1792;
    float* z   = ws + off; off += (size_t)G_ * 640;
    float* f1  = ws + off; off += (size_t)G_ * 128;
    int* rowptr = (int*)(ws + off); off += (size_t)(N + 1);
    int* colc   = (int*)(ws + off); off += (size_t)Etot;
    int* gptr   = (int*)(ws + off); off += (size_t)(G_ + 1);
    int* bsums  = (int*)(ws + off); off += 256;
    off = (off + 3) & ~(size_t)3;                 // 16B-align the bf16 tables
    unsigned short* vat1 = (unsigned short*)(ws + off); off += 128 * 64 / 2;
    unsigned short* vat2 = (unsigned short*)(ws + off); off += 128 * 512 / 2;
    unsigned short* W1bdt = (unsigned short*)(ws + off); off += 512 * 256 / 2;
    unsigned short* W2t = (unsigned short*)(ws + off); off += 512 * 1024 / 2;
    unsigned short* Wgt = (unsigned short*)(ws + off); off += 1024 * 256 / 2;
    int* cursor = (int*)alsd;   // alias: cursor dead before alsd is written
    size_t need = off * 4;
    if (ws_size < need) {
        sentinel<<<cdiv(out_size, 256), 256, 0, stream>>>(outp, out_size, (float)(ws_size >> 20));
        return;
    }

    const int BLK = 256;
    dim3 blk(BLK);

    // zero ALL atomic-stats regions ONCE, up front (overlaps prep/CSR work)
    hipMemsetAsync(ps, 0, (size_t)YB * 1920 * 4, stream);
    hipMemsetAsync(pq, 0, (size_t)YB * 1920 * 4, stream);

    // ============ MEGA-PREP (weights, x cast, vat, cursor, gptr) ============
    const int c0 = 512;
    const int c1 = c0 + 2048;
    const int c2 = c1 + 1024;
    const int c3 = c2 + cdiv((long long)N * 16, 256);
    const int c4 = c3 + 64;
    const int c5 = c4 + 512;
    const int c6 = c5 + cdiv(N, 256);
    const int c7 = c6 + cdiv(G_ + 1, 256);
    prep_all<<<c7, blk, 0, stream>>>(W1, W2, Wg, x, a1s, a1d, a2s, a2d, batch,
                                     W1bdt, W2t, Wgt, xb, vat1, vat2,
                                     cursor, gptr, N, G_,
                                     c0, c1, c2, c3, c4, c5, c6);

    // ================= build CSR (dst -> src) ===============================
    hist_dst<<<cdiv(E, BLK), blk, 0, stream>>>(edst, E, cursor);
    scan_blk<<<NB, blk, 0, stream>>>(cursor, rowptr, bsums, N);
    scan_tops<<<1, blk, 0, stream>>>(bsums, rowptr, NB, N);
    scan_add<<<cdiv(N, BLK), blk, 0, stream>>>(rowptr, cursor, bsums, N);
    { int NBsc = cdiv(Etot, BLK);
      csr_scatter_dinv<<<NBsc + cdiv(N, BLK), blk, 0, stream>>>(
          esrc, edst, E, Etot, cursor, colc, rowptr, dinv, N, NBsc); }

    // ====== GAT layer 1: logits -> agg(x, exp inline) -> GEMM (stats fused) =
    logits_valu<<<cdiv(N, 32), blk, 0, stream>>>(xb, vat1, alsd, N, 64);
    gat_agg4_64<<<cdiv((long long)N * 64, BLK), blk, 0, stream>>>(
        rowptr, colc, xb, alsd, hb, N);
    gemm_mfma<<<NYT8 * 4, blk, 0, stream>>>(hb, W1bdt, g1b, N, 256, 256, 256, 512, 4, NYT,
                                            ps, pq, 512);
    bn_reduce_fin<512><<<8, blk, 0, stream>>>(ps, pq, bn1g, bn1b, bsc, bsh, YB, 1.f / N);
    // fused: relu(bn(g1b)) -> o1n  AND layer-2 logits -> alsd (persistent blocks)
    bn_apply_logits512<<<2048, blk, 0, stream>>>(
        g1b, bsc, bsh, vat2, o1n, alsd, N, 2048);

    // ======= GAT layer 2: ONE batched GEMM (512 -> 1024), XCD-swizzled =====
    gemm_mfma<<<NYT8 * 8, blk, 0, stream>>>(o1n, W2t, h2all, N, 512, 512, 512, 1024, 8, NYT,
                                            nullptr, nullptr, 0);
    // R1 (o1n) dead after the GEMM: head-pair gathers (exp + BN-stats fused)
    // -> R1; fin; apply back into h2all column block. Per-site stats regions.
    for (int pr = 0; pr < 2; ++pr) {
        float* pssite = pr ? psP1 : psP0;
        float* pqsite = pr ? pqP1 : pqP0;
        gat_gather512_ex<<<cdiv((long long)N * 64, BLK), blk, 0, stream>>>(
            rowptr, colc, h2all + pr * 512, 1024, alsd, pr, R1, pssite, pqsite, N);
        bn_reduce_fin<512><<<8, blk, 0, stream>>>(pssite, pqsite, bn2g + pr * 512, bn2b + pr * 512,
                                                  bsc + pr * 512, bsh + pr * 512, YB, 1.f / N);
        bn_apply_bfbf<<<cdiv((long long)N * 128, BLK), blk, 0, stream>>>(
            R1, bsc + pr * 512, bsh + pr * 512, h2all + pr * 512, N * 128, 128, 512, 1024);
    }

    // GCN GEMM: K=1024, 2 column blocks, XCD-swizzled (A read ~once)
    gemm_mfma<<<NYT8 * 2, blk, 0, stream>>>(h2all, Wgt, hb, N, 1024, 1024, 1024, 256, 2, NYT,
                                            nullptr, nullptr, 0);

    // ================= GCN aggregation (BN3 stats fused) ====================
    gcn_gather256<<<cdiv((long long)N * 64, BLK), blk, 0, stream>>>(
        rowptr, colc, hb, dinv, g3b, psG, pqG, N);
    bn_reduce_fin<256><<<4, blk, 0, stream>>>(psG, pqG, bn3g, bn3b, bsc, bsh, YB, 1.f / N);

    // ======== Pooling (BN3+relu fused) + solvent MLP, ONE launch ============
    pool_solv<<<G_ + cdiv(G_, 2), blk, 0, stream>>>(
        g3b, bsc, bsh, gptr, z, G_, sfp, Wsm, bsm);

    // ================= Head (BNf stats fused into the GEMM epilogue) ========
    gemm_small<false><<<cdiv(G_, 2), blk, 0, stream>>>(
        z, Wf1, nullptr, f1, G_, 640, 640, 128, 128, psF, pqF);
    bn_reduce_fin<128><<<2, blk, 0, stream>>>(psF, pqF, bnfg, bnfb, bsc, bsh, YB, 1.f / G_);
    final_head_bn<<<cdiv((long long)G_ * 64, BLK), blk, 0, stream>>>(
        f1, bsc, bsh, Wf2, bf2, outp, G_);
}